// Round 4
// baseline (1027.669 us; speedup 1.0000x reference)
//
#include <hip/hip_runtime.h>

// ---------------------------------------------------------------------------
// EncoderLayer (MatNet-style mixed-score MHA) for MI355X.
// Shapes: B=16, NO=512, NM=128, NV=64, E=256, H=16, DK=16, MS=8, FF=512.
// Dtype policy (R4): inputs f32, masks int32, OUTPUT f32 (reference returns
// jnp.float32; R2/R3's 7.28 absmax == bf16-written/f32-read signature).
// Intermediates bf16 in workspace (threshold is bf16-floored: 0.10875).
// ---------------------------------------------------------------------------

typedef unsigned short u16;

__device__ __forceinline__ float bf2f(u16 u) {
  return __uint_as_float(((unsigned int)u) << 16);
}
__device__ __forceinline__ u16 f2bf(float f) {
  unsigned int x = __float_as_uint(f);
  x += 0x7FFFu + ((x >> 16) & 1u);   // round-to-nearest-even
  return (u16)(x >> 16);
}
__device__ __forceinline__ float ldf(const float* p) { return *p; }
__device__ __forceinline__ float ldf(const u16* p) { return bf2f(*p); }
__device__ __forceinline__ void stf(float* p, float v) { *p = v; }
__device__ __forceinline__ void stf(u16* p, float v) { *p = f2bf(v); }

#define NBATCH 16
#define NOPE   512
#define NMA    128
#define NVEH   64
#define EDIM   256

// ---------------------------------------------------------------------------
// A_proc_norm: per (b,o) row over 128 machines: 1.0 where masked proc_time
// equals the row-min of nonzero masked entries, else 0.
// ---------------------------------------------------------------------------
__global__ __launch_bounds__(128) void aproc_kernel(
    const float* __restrict__ proc, const int* __restrict__ mask,
    float* __restrict__ out) {
  int row = blockIdx.x;
  int t = threadIdx.x;
  size_t idx = (size_t)row * NMA + t;
  float a = mask[idx] ? proc[idx] : 0.0f;
  float cand = (a != 0.0f) ? a : 1.0e30f;
  __shared__ float red[128];
  red[t] = cand;
  __syncthreads();
  for (int s = 64; s > 0; s >>= 1) {
    if (t < s) red[t] = fminf(red[t], red[t + s]);
    __syncthreads();
  }
  float mn = red[0];
  out[idx] = (a != 0.0f && a == mn) ? 1.0f : 0.0f;
}

// ---------------------------------------------------------------------------
// A_off = 1 - minmax-norm(MVpair_trans) per batch (over NV*NM elements).
// ---------------------------------------------------------------------------
__global__ __launch_bounds__(256) void aoff_kernel(
    const float* __restrict__ x, float* __restrict__ out, int n) {
  int b = blockIdx.x, t = threadIdx.x;
  const float* xb = x + (size_t)b * n;
  float mn = 1.0e30f, mx = -1.0e30f;
  for (int i = t; i < n; i += 256) {
    float v = xb[i];
    mn = fminf(mn, v);
    mx = fmaxf(mx, v);
  }
  __shared__ float smn[256], smx[256];
  smn[t] = mn; smx[t] = mx;
  __syncthreads();
  for (int s = 128; s > 0; s >>= 1) {
    if (t < s) {
      smn[t] = fminf(smn[t], smn[t + s]);
      smx[t] = fmaxf(smx[t], smx[t + s]);
    }
    __syncthreads();
  }
  float lo = smn[0], hi = smx[0];
  float inv = 1.0f / (hi - lo);
  for (int i = t; i < n; i += 256)
    out[(size_t)b * n + i] = 1.0f - (xb[i] - lo) * inv;
}

// ---------------------------------------------------------------------------
// A_on (masked trans_time inv-norm) + A_procing (~mask2) per batch.
// ---------------------------------------------------------------------------
__global__ __launch_bounds__(256) void aon_kernel(
    const float* __restrict__ trans, const int* __restrict__ mask_ma,
    float* __restrict__ a_on, float* __restrict__ a_pcing) {
  int b = blockIdx.x, t = threadIdx.x;
  __shared__ unsigned char mrow[NMA];
  if (t < NMA) mrow[t] = (unsigned char)(mask_ma[(size_t)b * NMA + t] != 0);
  __syncthreads();
  const float* tb = trans + (size_t)b * NMA * NMA;
  float mn = 1.0e30f, mx = -1.0e30f;
  for (int idx = t; idx < NMA * NMA; idx += 256) {
    int i = idx >> 7, j = idx & 127;
    bool m2 = mrow[i] && mrow[j];
    float tt = m2 ? tb[idx] : 101.0f;
    mn = fminf(mn, tt);
    mx = fmaxf(mx, tt);
  }
  __shared__ float smn[256], smx[256];
  smn[t] = mn; smx[t] = mx;
  __syncthreads();
  for (int s = 128; s > 0; s >>= 1) {
    if (t < s) {
      smn[t] = fminf(smn[t], smn[t + s]);
      smx[t] = fmaxf(smx[t], smx[t + s]);
    }
    __syncthreads();
  }
  float lo = smn[0], hi = smx[0];
  float inv = 1.0f / (hi - lo);
  for (int idx = t; idx < NMA * NMA; idx += 256) {
    int i = idx >> 7, j = idx & 127;
    bool m2 = mrow[i] && mrow[j];
    float tt = m2 ? tb[idx] : 101.0f;
    a_on[(size_t)b * NMA * NMA + idx] = 1.0f - (tt - lo) * inv;
    a_pcing[(size_t)b * NMA * NMA + idx] = m2 ? 0.0f : 1.0f;
  }
}

// ---------------------------------------------------------------------------
// Generic GEMM: C[M,N] = A[M,K] @ W[K,N] (+bias) (relu). A is f32 or bf16,
// W/bias f32, acc f32. epi: 0=none, 1=+bias, 2=+bias+relu.
// Store f32 (Cf) if non-null else bf16 (Cb). M%64==0, N%64==0, K%16==0.
// 64x64 tile, 256 threads, 4x4 per thread.
// ---------------------------------------------------------------------------
template <typename TA>
__global__ __launch_bounds__(256) void gemm64(
    const TA* __restrict__ A, const float* __restrict__ W,
    const float* __restrict__ bias, float* __restrict__ Cf,
    u16* __restrict__ Cb, int M, int N, int K, int epi) {
  __shared__ float As[16][64];
  __shared__ float Bs[16][64];
  int tid = threadIdx.x;
  int tx = tid & 15, ty = tid >> 4;
  int rb = blockIdx.y * 64, cb = blockIdx.x * 64;
  float acc[4][4];
#pragma unroll
  for (int i = 0; i < 4; i++)
#pragma unroll
    for (int j = 0; j < 4; j++) acc[i][j] = 0.0f;

  int ar = tid >> 2, ac = (tid & 3) * 4;
  int wr = tid >> 4, wc = (tid & 15) * 4;
  for (int k0 = 0; k0 < K; k0 += 16) {
    const TA* ap = A + (size_t)(rb + ar) * K + k0 + ac;
#pragma unroll
    for (int j = 0; j < 4; j++) As[ac + j][ar] = ldf(ap + j);
    const float* wp = W + (size_t)(k0 + wr) * N + cb + wc;
#pragma unroll
    for (int j = 0; j < 4; j++) Bs[wr][wc + j] = wp[j];
    __syncthreads();
#pragma unroll
    for (int kk = 0; kk < 16; kk++) {
      float a[4], b[4];
#pragma unroll
      for (int i = 0; i < 4; i++) a[i] = As[kk][ty + 16 * i];
#pragma unroll
      for (int j = 0; j < 4; j++) b[j] = Bs[kk][tx + 16 * j];
#pragma unroll
      for (int i = 0; i < 4; i++)
#pragma unroll
        for (int j = 0; j < 4; j++) acc[i][j] += a[i] * b[j];
    }
    __syncthreads();
  }
#pragma unroll
  for (int i = 0; i < 4; i++) {
    int row = rb + ty + 16 * i;
#pragma unroll
    for (int j = 0; j < 4; j++) {
      int col = cb + tx + 16 * j;
      float v = acc[i][j];
      if (epi >= 1) v += bias[col];
      if (epi == 2) v = fmaxf(v, 0.0f);
      if (Cf) Cf[(size_t)row * N + col] = v;
      else    Cb[(size_t)row * N + col] = f2bf(v);
    }
  }
}

// ---------------------------------------------------------------------------
// Fused mixed-score attention for one (b, r) row: 16 heads x 128 columns.
// q,k,v: [*,256] bf16 (head h = cols h*16..h*16+15). cost: [M,128] f32.
// mix weights f32. grid = M blocks (M = B*R), 256 threads.
// ---------------------------------------------------------------------------
__global__ __launch_bounds__(256) void attn_kernel(
    const u16* __restrict__ q, const u16* __restrict__ k,
    const u16* __restrict__ v, const float* __restrict__ cost,
    const float* __restrict__ mixW1, const float* __restrict__ mixb1,
    const float* __restrict__ mixW2, const float* __restrict__ mixb2,
    u16* __restrict__ ctx, int R) {
  int m = blockIdx.x;
  int b = m / R;
  int t = threadIdx.x;
  __shared__ float qs[256];
  __shared__ float sc[16][132];           // stride 132 breaks bank alias
  __shared__ float w10[16][8], w11[16][8], wb1[16][8], w2s[16][8], wb2[16];
  __shared__ float pmax[16][16], psum[16][16];

  qs[t] = bf2f(q[(size_t)m * 256 + t]);
  if (t < 128) {
    int h = t >> 3, s = t & 7;
    w10[h][s] = mixW1[h * 16 + s];        // [h][0][s]
    w11[h][s] = mixW1[h * 16 + 8 + s];    // [h][1][s]
    wb1[h][s] = mixb1[t];
    w2s[h][s] = mixW2[t];
    if (s == 0) wb2[h] = mixb2[h];
  }
  __syncthreads();

  int h = t & 15, ci = t >> 4;            // thread covers cols ci*8..ci*8+7 of head h
  const float* costrow = cost + (size_t)m * 128;
  float myscore[8];
  float lmax = -1.0e30f;
#pragma unroll
  for (int u = 0; u < 8; u++) {
    int c = ci * 8 + u;
    const u16* kp = k + ((size_t)(b * 128 + c)) * 256 + h * 16;
    float dot = 0.0f;
#pragma unroll
    for (int d = 0; d < 16; d++) dot += qs[h * 16 + d] * bf2f(kp[d]);
    dot *= 0.25f;                          // 1/sqrt(DK)
    float co = costrow[c];
    float scv = wb2[h];
#pragma unroll
    for (int s = 0; s < 8; s++) {
      float hm = fmaxf(dot * w10[h][s] + co * w11[h][s] + wb1[h][s], 0.0f);
      scv += hm * w2s[h][s];
    }
    myscore[u] = scv;
    lmax = fmaxf(lmax, scv);
  }
  pmax[h][ci] = lmax;
  __syncthreads();
  float mx = -1.0e30f;
#pragma unroll
  for (int i2 = 0; i2 < 16; i2++) mx = fmaxf(mx, pmax[h][i2]);
  float lsum = 0.0f;
#pragma unroll
  for (int u = 0; u < 8; u++) {
    float e = __expf(myscore[u] - mx);
    sc[h][ci * 8 + u] = e;
    lsum += e;
  }
  psum[h][ci] = lsum;
  __syncthreads();
  float ssum = 0.0f;
#pragma unroll
  for (int i2 = 0; i2 < 16; i2++) ssum += psum[h][i2];
  float inv = 1.0f / ssum;
#pragma unroll
  for (int u = 0; u < 8; u++) sc[h][ci * 8 + u] *= inv;
  __syncthreads();

  // ctx[m, t] = sum_c attn[h2][c] * v[b, c, t], h2 = t>>4
  int h2 = t >> 4;
  const u16* vb = v + (size_t)(b * 128) * 256 + t;
  float acc = 0.0f;
  for (int c = 0; c < 128; c++) acc += sc[h2][c] * bf2f(vb[(size_t)c * 256]);
  ctx[(size_t)m * 256 + t] = f2bf(acc);
}

// ---------------------------------------------------------------------------
// Residual + LayerNorm over E=256: out[row*ostride+ooff+t] = LN(resid + x).
// resid f32 (embeddings) or bf16 (out1); x f32; out f32 (d_out) or bf16 (ws).
// ---------------------------------------------------------------------------
template <typename TR, typename TO>
__global__ __launch_bounds__(256) void ln_kernel(
    const TR* __restrict__ resid, const float* __restrict__ x,
    TO* __restrict__ out, int ostride, int ooff) {
  int row = blockIdx.x, t = threadIdx.x;
  float vv = ldf(resid + (size_t)row * 256 + t) + x[(size_t)row * 256 + t];
  __shared__ float red[256];
  red[t] = vv;
  __syncthreads();
  for (int s = 128; s > 0; s >>= 1) {
    if (t < s) red[t] += red[t + s];
    __syncthreads();
  }
  float mean = red[0] * (1.0f / 256.0f);
  __syncthreads();
  float d = vv - mean;
  red[t] = d * d;
  __syncthreads();
  for (int s = 128; s > 0; s >>= 1) {
    if (t < s) red[t] += red[t + s];
    __syncthreads();
  }
  float var = red[0] * (1.0f / 256.0f);
  float y = d * rsqrtf(var + 1e-5f);
  stf(out + (size_t)row * ostride + ooff + t, y);
}

// ---------------------------------------------------------------------------
extern "C" void kernel_launch(void* const* d_in, const int* in_sizes, int n_in,
                              void* d_out, int out_size, void* d_ws, size_t ws_size,
                              hipStream_t stream) {
  const float* ope   = (const float*)d_in[0];
  const float* ma    = (const float*)d_in[1];
  const float* veh   = (const float*)d_in[2];
  const float* proc  = (const float*)d_in[3];
  // d_in[4] offload_trans_time: unused by reference
  const float* trans = (const float*)d_in[5];
  const float* mv    = (const float*)d_in[6];
  const int* mask_dyn = (const int*)d_in[7];
  const int* mask_ma  = (const int*)d_in[8];
  const float* Wq = (const float*)d_in[9];
  const float* Wk = (const float*)d_in[10];
  const float* Wv = (const float*)d_in[11];
  const float* Wo = (const float*)d_in[12];
  const float* mixW1 = (const float*)d_in[13];
  const float* mixb1 = (const float*)d_in[14];
  const float* mixW2 = (const float*)d_in[15];
  const float* mixb2 = (const float*)d_in[16];
  const float* ffW1 = (const float*)d_in[17];
  const float* ffb1 = (const float*)d_in[18];
  const float* ffW2 = (const float*)d_in[19];
  const float* ffb2 = (const float*)d_in[20];
  const float* maprojW = (const float*)d_in[21];
  const float* maprojb = (const float*)d_in[22];
  float* out = (float*)d_out;               // f32 output (reference dtype)
  char* ws = (char*)d_ws;

  // Workspace layout (27.5 MB) with time-disjoint aliasing:
  //   R0 [0, 8MB):        A_proc (4MB, alive until block0 attn) then t1 (f32 8MB)
  //   R1 [8, 8.5):        A_offb f32
  //   R2 [8.5, 9.5):      A_pcing f32
  //   R3 [9.5, 10.5):     A_on f32
  //   R4 [10.5, 12.5):    maCat bf16 [2048,512]
  //   R5 [12.5, 13.5):    k_buf bf16 [2048,256]
  //   R6 [13.5, 14.5):    v_buf bf16 [2048,256]
  //   R7 [14.5, 18.5):    q_buf bf16 (dead after attn) / out1 bf16 (ln1 output)
  //   R8 [18.5, 26.5):    ctx bf16 (dead after Wo-gemm) / ffh bf16 [8192,512]
  const size_t MB = 1 << 20;
  float* A_proc  = (float*)(ws + 0);
  float* t1      = (float*)(ws + 0);
  float* A_offb  = (float*)(ws + 8 * MB);
  float* A_pcing = (float*)(ws + (8 * MB + MB / 2));
  float* A_on    = (float*)(ws + (9 * MB + MB / 2));
  u16*   maCat   = (u16*)  (ws + (10 * MB + MB / 2));
  u16*   k_buf   = (u16*)  (ws + (12 * MB + MB / 2));
  u16*   v_buf   = (u16*)  (ws + (13 * MB + MB / 2));
  u16*   q_buf   = (u16*)  (ws + (14 * MB + MB / 2));
  u16*   out1    = (u16*)  (ws + (14 * MB + MB / 2));
  u16*   ctx_buf = (u16*)  (ws + (18 * MB + MB / 2));
  u16*   ffh     = (u16*)  (ws + (18 * MB + MB / 2));

  // adjacency
  aproc_kernel<<<NBATCH * NOPE, 128, 0, stream>>>(proc, mask_dyn, A_proc);
  aoff_kernel<<<NBATCH, 256, 0, stream>>>(mv, A_offb, NVEH * NMA);
  aon_kernel<<<NBATCH, 256, 0, stream>>>(trans, mask_ma, A_on, A_pcing);

  const size_t OPE_OUT = 0;
  const size_t MA_OUT  = (size_t)NBATCH * NOPE * EDIM;            // 2097152
  const size_t VEH_OUT = MA_OUT + (size_t)NBATCH * NMA * EDIM;    // 2621440

  // dest_f: non-null -> ln2 writes f32 there; else writes bf16 to dest_b.
  auto run_block = [&](int i, const float* row, int M, int R, const float* cost,
                       float* dest_f, u16* dest_b, int dstride, int doff) {
    gemm64<float><<<dim3(4, M / 64), 256, 0, stream>>>(row, Wq + (size_t)i * 65536,
        nullptr, nullptr, q_buf, M, 256, 256, 0);
    gemm64<float><<<dim3(4, 32), 256, 0, stream>>>(ma, Wk + (size_t)i * 65536,
        nullptr, nullptr, k_buf, 2048, 256, 256, 0);
    gemm64<float><<<dim3(4, 32), 256, 0, stream>>>(ma, Wv + (size_t)i * 65536,
        nullptr, nullptr, v_buf, 2048, 256, 256, 0);
    attn_kernel<<<M, 256, 0, stream>>>(q_buf, k_buf, v_buf, cost,
        mixW1 + (size_t)i * 256, mixb1 + (size_t)i * 128,
        mixW2 + (size_t)i * 128, mixb2 + (size_t)i * 16, ctx_buf, R);
    gemm64<u16><<<dim3(4, M / 64), 256, 0, stream>>>(ctx_buf, Wo + (size_t)i * 65536,
        nullptr, t1, nullptr, M, 256, 256, 0);
    ln_kernel<float, u16><<<M, 256, 0, stream>>>(row, t1, out1, 256, 0);
    gemm64<u16><<<dim3(8, M / 64), 256, 0, stream>>>(out1, ffW1 + (size_t)i * 131072,
        ffb1 + (size_t)i * 512, nullptr, ffh, M, 512, 256, 2);
    gemm64<u16><<<dim3(4, M / 64), 256, 0, stream>>>(ffh, ffW2 + (size_t)i * 131072,
        ffb2 + (size_t)i * 256, t1, nullptr, M, 256, 512, 1);
    if (dest_f)
      ln_kernel<u16, float><<<M, 256, 0, stream>>>(out1, t1, dest_f, dstride, doff);
    else
      ln_kernel<u16, u16><<<M, 256, 0, stream>>>(out1, t1, dest_b, dstride, doff);
  };

  run_block(0, ope, NBATCH * NOPE, NOPE, A_proc,  out + OPE_OUT, nullptr, 256, 0);
  run_block(1, veh, NBATCH * NVEH, NVEH, A_offb,  out + VEH_OUT, nullptr, 256, 0);
  run_block(2, ma,  NBATCH * NMA,  NMA,  A_pcing, nullptr, maCat, 512, 0);
  run_block(3, ma,  NBATCH * NMA,  NMA,  A_on,    nullptr, maCat, 512, 256);

  // ma_out (f32) = concat(ma1, ma2) @ maprojW + maprojb
  gemm64<u16><<<dim3(4, 32), 256, 0, stream>>>(maCat, maprojW, maprojb,
      out + MA_OUT, nullptr, 2048, 256, 512, 1);
}

// Round 5
// 695.396 us; speedup vs baseline: 1.4778x; 1.4778x over previous
//
#include <hip/hip_runtime.h>

// ---------------------------------------------------------------------------
// EncoderLayer (MatNet mixed-score MHA) for MI355X — R5: MFMA GEMMs.
// B=16, NO=512, NM=128, NV=64, E=256, H=16, DK=16, MS=8, FF=512.
// Inputs f32, masks int32, d_out f32 (confirmed R4, absmax 0.031).
// Pipeline: one-time f32->bf16 converts (+ weight transposes), then
// 128x128-tile 16x16x32-bf16 MFMA GEMMs, fused attn (lane roles swapped to
// kill the 32-way qs bank conflict), residual+LN kernels.
// ---------------------------------------------------------------------------

typedef unsigned short u16;
typedef __attribute__((ext_vector_type(8))) short bf16x8;
typedef __attribute__((ext_vector_type(4))) float f32x4;
struct us4 { u16 x, y, z, w; };

__device__ __forceinline__ float bf2f(u16 u) {
  return __uint_as_float(((unsigned int)u) << 16);
}
__device__ __forceinline__ u16 f2bf(float f) {
  unsigned int x = __float_as_uint(f);
  x += 0x7FFFu + ((x >> 16) & 1u);   // round-to-nearest-even
  return (u16)(x >> 16);
}
__device__ __forceinline__ float ldf(const float* p) { return *p; }
__device__ __forceinline__ float ldf(const u16* p) { return bf2f(*p); }
__device__ __forceinline__ void stf(float* p, float v) { *p = v; }
__device__ __forceinline__ void stf(u16* p, float v) { *p = f2bf(v); }

#define NBATCH 16
#define NOPE   512
#define NMA    128
#define NVEH   64
#define EDIM   256

// ---------------------------------------------------------------------------
// f32 -> bf16 elementwise convert (n % 4 == 0).
// ---------------------------------------------------------------------------
__global__ __launch_bounds__(256) void cvt_bf16(
    const float* __restrict__ src, u16* __restrict__ dst, int n4) {
  int i = blockIdx.x * 256 + threadIdx.x;
  if (i >= n4) return;
  float4 v = ((const float4*)src)[i];
  us4 o = { f2bf(v.x), f2bf(v.y), f2bf(v.z), f2bf(v.w) };
  ((us4*)dst)[i] = o;
}

// ---------------------------------------------------------------------------
// W [z][Kd][Nd] f32  ->  WT [z][Nd][Kd] bf16.  Kd,Nd % 32 == 0.
// grid (Kd/32, Nd/32, z), 256 threads.
// ---------------------------------------------------------------------------
__global__ __launch_bounds__(256) void transpose_bf16(
    const float* __restrict__ src, u16* __restrict__ dst, int Kd, int Nd) {
  size_t zo = (size_t)blockIdx.z * Kd * Nd;
  src += zo; dst += zo;
  __shared__ float tile[32][33];
  int k0 = blockIdx.x * 32, n0 = blockIdx.y * 32;
  int tx = threadIdx.x & 31, ty = threadIdx.x >> 5;   // ty 0..7
#pragma unroll
  for (int r = 0; r < 4; r++)
    tile[ty + r * 8][tx] = src[(size_t)(k0 + ty + r * 8) * Nd + n0 + tx];
  __syncthreads();
#pragma unroll
  for (int r = 0; r < 4; r++)
    dst[(size_t)(n0 + ty + r * 8) * Kd + k0 + tx] = f2bf(tile[tx][ty + r * 8]);
}

// ---------------------------------------------------------------------------
// Adjacency kernels (unchanged from R4).
// ---------------------------------------------------------------------------
__global__ __launch_bounds__(128) void aproc_kernel(
    const float* __restrict__ proc, const int* __restrict__ mask,
    float* __restrict__ out) {
  int row = blockIdx.x;
  int t = threadIdx.x;
  size_t idx = (size_t)row * NMA + t;
  float a = mask[idx] ? proc[idx] : 0.0f;
  float cand = (a != 0.0f) ? a : 1.0e30f;
  __shared__ float red[128];
  red[t] = cand;
  __syncthreads();
  for (int s = 64; s > 0; s >>= 1) {
    if (t < s) red[t] = fminf(red[t], red[t + s]);
    __syncthreads();
  }
  float mn = red[0];
  out[idx] = (a != 0.0f && a == mn) ? 1.0f : 0.0f;
}

__global__ __launch_bounds__(256) void aoff_kernel(
    const float* __restrict__ x, float* __restrict__ out, int n) {
  int b = blockIdx.x, t = threadIdx.x;
  const float* xb = x + (size_t)b * n;
  float mn = 1.0e30f, mx = -1.0e30f;
  for (int i = t; i < n; i += 256) {
    float v = xb[i];
    mn = fminf(mn, v);
    mx = fmaxf(mx, v);
  }
  __shared__ float smn[256], smx[256];
  smn[t] = mn; smx[t] = mx;
  __syncthreads();
  for (int s = 128; s > 0; s >>= 1) {
    if (t < s) {
      smn[t] = fminf(smn[t], smn[t + s]);
      smx[t] = fmaxf(smx[t], smx[t + s]);
    }
    __syncthreads();
  }
  float lo = smn[0], hi = smx[0];
  float inv = 1.0f / (hi - lo);
  for (int i = t; i < n; i += 256)
    out[(size_t)b * n + i] = 1.0f - (xb[i] - lo) * inv;
}

__global__ __launch_bounds__(256) void aon_kernel(
    const float* __restrict__ trans, const int* __restrict__ mask_ma,
    float* __restrict__ a_on, float* __restrict__ a_pcing) {
  int b = blockIdx.x, t = threadIdx.x;
  __shared__ unsigned char mrow[NMA];
  if (t < NMA) mrow[t] = (unsigned char)(mask_ma[(size_t)b * NMA + t] != 0);
  __syncthreads();
  const float* tb = trans + (size_t)b * NMA * NMA;
  float mn = 1.0e30f, mx = -1.0e30f;
  for (int idx = t; idx < NMA * NMA; idx += 256) {
    int i = idx >> 7, j = idx & 127;
    bool m2 = mrow[i] && mrow[j];
    float tt = m2 ? tb[idx] : 101.0f;
    mn = fminf(mn, tt);
    mx = fmaxf(mx, tt);
  }
  __shared__ float smn[256], smx[256];
  smn[t] = mn; smx[t] = mx;
  __syncthreads();
  for (int s = 128; s > 0; s >>= 1) {
    if (t < s) {
      smn[t] = fminf(smn[t], smn[t + s]);
      smx[t] = fmaxf(smx[t], smx[t + s]);
    }
    __syncthreads();
  }
  float lo = smn[0], hi = smx[0];
  float inv = 1.0f / (hi - lo);
  for (int idx = t; idx < NMA * NMA; idx += 256) {
    int i = idx >> 7, j = idx & 127;
    bool m2 = mrow[i] && mrow[j];
    float tt = m2 ? tb[idx] : 101.0f;
    a_on[(size_t)b * NMA * NMA + idx] = 1.0f - (tt - lo) * inv;
    a_pcing[(size_t)b * NMA * NMA + idx] = m2 ? 0.0f : 1.0f;
  }
}

// ---------------------------------------------------------------------------
// MFMA GEMM: C[M,N] = A[M,K] @ W[K,N] via WT[N,K], bf16 inputs, f32 acc.
// 128x128 tile, 4 waves, each wave 64x64 (4x4 grid of 16x16x32 MFMAs).
// LDS rows padded to 40 bf16 (80 B): stage-writes and frag-reads are 2-way
// (free, m136). epi: 0 none, 1 +bias, 2 +bias+relu. TO = u16 (bf16) or float.
// Requires M%128==0, N%128==0, K%32==0.
// ---------------------------------------------------------------------------
template <typename TO>
__global__ __launch_bounds__(256) void gemm_mfma(
    const u16* __restrict__ A, const u16* __restrict__ WT,
    const float* __restrict__ bias, TO* __restrict__ C,
    int M, int N, int K, int epi) {
  __shared__ u16 As[128][40];
  __shared__ u16 Bs[128][40];
  int tid = threadIdx.x;
  int lane = tid & 63, wid = tid >> 6;
  int wr = (wid >> 1) * 64, wc = (wid & 1) * 64;
  int m16 = lane & 15, quad = lane >> 4;
  int rb = blockIdx.y * 128, cb = blockIdx.x * 128;
  int srow = tid >> 2;            // 0..63
  int schunk = (tid & 3) * 8;     // bf16 offset within 32-wide k-slab

  f32x4 acc[4][4];
#pragma unroll
  for (int i = 0; i < 4; i++)
#pragma unroll
    for (int j = 0; j < 4; j++) acc[i][j] = (f32x4){0.f, 0.f, 0.f, 0.f};

  for (int k0 = 0; k0 < K; k0 += 32) {
    uint4 va0 = *(const uint4*)(A + (size_t)(rb + srow) * K + k0 + schunk);
    uint4 va1 = *(const uint4*)(A + (size_t)(rb + 64 + srow) * K + k0 + schunk);
    uint4 vb0 = *(const uint4*)(WT + (size_t)(cb + srow) * K + k0 + schunk);
    uint4 vb1 = *(const uint4*)(WT + (size_t)(cb + 64 + srow) * K + k0 + schunk);
    __syncthreads();             // previous iter's frag reads complete
    *(uint4*)&As[srow][schunk] = va0;
    *(uint4*)&As[64 + srow][schunk] = va1;
    *(uint4*)&Bs[srow][schunk] = vb0;
    *(uint4*)&Bs[64 + srow][schunk] = vb1;
    __syncthreads();
    bf16x8 af[4], bfr[4];
#pragma unroll
    for (int i = 0; i < 4; i++)
      af[i] = *(const bf16x8*)&As[wr + i * 16 + m16][quad * 8];
#pragma unroll
    for (int j = 0; j < 4; j++)
      bfr[j] = *(const bf16x8*)&Bs[wc + j * 16 + m16][quad * 8];
#pragma unroll
    for (int i = 0; i < 4; i++)
#pragma unroll
      for (int j = 0; j < 4; j++)
        acc[i][j] = __builtin_amdgcn_mfma_f32_16x16x32_bf16(
            af[i], bfr[j], acc[i][j], 0, 0, 0);
  }

#pragma unroll
  for (int i = 0; i < 4; i++) {
#pragma unroll
    for (int j = 0; j < 4; j++) {
      int col = cb + wc + j * 16 + m16;
      float bv = (epi >= 1) ? bias[col] : 0.0f;
#pragma unroll
      for (int r = 0; r < 4; r++) {
        int row = rb + wr + i * 16 + quad * 4 + r;
        float v = acc[i][j][r] + bv;
        if (epi == 2) v = fmaxf(v, 0.0f);
        stf(&C[(size_t)row * N + col], v);
      }
    }
  }
}

// ---------------------------------------------------------------------------
// Fused mixed-score attention, one (b,r) row: 16 heads x 128 cols.
// Lane roles: h = t>>4 (qs reads become wave-uniform broadcasts, free),
// ci = t&15. sc stride 133: head-rows land on disjoint bank quartets (4-way
// max on score writes). q,k,v bf16; cost f32; mix weights f32.
// ---------------------------------------------------------------------------
__global__ __launch_bounds__(256) void attn_kernel(
    const u16* __restrict__ q, const u16* __restrict__ k,
    const u16* __restrict__ v, const float* __restrict__ cost,
    const float* __restrict__ mixW1, const float* __restrict__ mixb1,
    const float* __restrict__ mixW2, const float* __restrict__ mixb2,
    u16* __restrict__ ctx, int R) {
  int m = blockIdx.x;
  int b = m / R;
  int t = threadIdx.x;
  __shared__ float qs[256];
  __shared__ float sc[16][133];
  __shared__ float w10[16][8], w11[16][8], wb1[16][8], w2s[16][8], wb2[16];
  __shared__ float pmax[16][16], psum[16][16];

  qs[t] = bf2f(q[(size_t)m * 256 + t]);
  if (t < 128) {
    int h = t >> 3, s = t & 7;
    w10[h][s] = mixW1[h * 16 + s];        // [h][0][s]
    w11[h][s] = mixW1[h * 16 + 8 + s];    // [h][1][s]
    wb1[h][s] = mixb1[t];
    w2s[h][s] = mixW2[t];
    if (s == 0) wb2[h] = mixb2[h];
  }
  __syncthreads();

  int h = t >> 4, ci = t & 15;            // head h, cols ci*8..ci*8+7
  const float* costrow = cost + (size_t)m * 128;
  float myscore[8];
  float lmax = -1.0e30f;
#pragma unroll
  for (int u = 0; u < 8; u++) {
    int c = ci * 8 + u;
    const u16* kp = k + ((size_t)(b * 128 + c)) * 256 + h * 16;
    float dot = 0.0f;
#pragma unroll
    for (int d = 0; d < 16; d++) dot += qs[h * 16 + d] * bf2f(kp[d]);
    dot *= 0.25f;                          // 1/sqrt(DK)
    float co = costrow[c];
    float scv = wb2[h];
#pragma unroll
    for (int s = 0; s < 8; s++) {
      float hm = fmaxf(dot * w10[h][s] + co * w11[h][s] + wb1[h][s], 0.0f);
      scv += hm * w2s[h][s];
    }
    myscore[u] = scv;
    lmax = fmaxf(lmax, scv);
  }
  pmax[h][ci] = lmax;
  __syncthreads();
  float mx = -1.0e30f;
#pragma unroll
  for (int i2 = 0; i2 < 16; i2++) mx = fmaxf(mx, pmax[h][i2]);
  float lsum = 0.0f;
#pragma unroll
  for (int u = 0; u < 8; u++) {
    float e = __expf(myscore[u] - mx);
    sc[h][ci * 8 + u] = e;
    lsum += e;
  }
  psum[h][ci] = lsum;
  __syncthreads();
  float ssum = 0.0f;
#pragma unroll
  for (int i2 = 0; i2 < 16; i2++) ssum += psum[h][i2];
  float inv = 1.0f / ssum;
#pragma unroll
  for (int u = 0; u < 8; u++) sc[h][ci * 8 + u] *= inv;
  __syncthreads();

  // ctx[m, t] = sum_c attn[h][c] * v[b, c, t]; sc reads broadcast per group.
  const u16* vb = v + (size_t)(b * 128) * 256 + t;
  float acc = 0.0f;
  for (int c = 0; c < 128; c++) acc += sc[h][c] * bf2f(vb[(size_t)c * 256]);
  ctx[(size_t)m * 256 + t] = f2bf(acc);
}

// ---------------------------------------------------------------------------
// Residual + LayerNorm over E=256. resid f32 (orig emb) or bf16; x bf16.
// ---------------------------------------------------------------------------
template <typename TR, typename TO>
__global__ __launch_bounds__(256) void ln_kernel(
    const TR* __restrict__ resid, const u16* __restrict__ x,
    TO* __restrict__ out, int ostride, int ooff) {
  int row = blockIdx.x, t = threadIdx.x;
  float vv = ldf(resid + (size_t)row * 256 + t) + bf2f(x[(size_t)row * 256 + t]);
  __shared__ float red[256];
  red[t] = vv;
  __syncthreads();
  for (int s = 128; s > 0; s >>= 1) {
    if (t < s) red[t] += red[t + s];
    __syncthreads();
  }
  float mean = red[0] * (1.0f / 256.0f);
  __syncthreads();
  float d = vv - mean;
  red[t] = d * d;
  __syncthreads();
  for (int s = 128; s > 0; s >>= 1) {
    if (t < s) red[t] += red[t + s];
    __syncthreads();
  }
  float var = red[0] * (1.0f / 256.0f);
  float y = d * rsqrtf(var + 1e-5f);
  stf(out + (size_t)row * ostride + ooff + t, y);
}

// ---------------------------------------------------------------------------
extern "C" void kernel_launch(void* const* d_in, const int* in_sizes, int n_in,
                              void* d_out, int out_size, void* d_ws, size_t ws_size,
                              hipStream_t stream) {
  const float* ope   = (const float*)d_in[0];
  const float* ma    = (const float*)d_in[1];
  const float* veh   = (const float*)d_in[2];
  const float* proc  = (const float*)d_in[3];
  const float* trans = (const float*)d_in[5];
  const float* mv    = (const float*)d_in[6];
  const int* mask_dyn = (const int*)d_in[7];
  const int* mask_ma  = (const int*)d_in[8];
  const float* Wq = (const float*)d_in[9];
  const float* Wk = (const float*)d_in[10];
  const float* Wv = (const float*)d_in[11];
  const float* Wo = (const float*)d_in[12];
  const float* mixW1 = (const float*)d_in[13];
  const float* mixb1 = (const float*)d_in[14];
  const float* mixW2 = (const float*)d_in[15];
  const float* mixb2 = (const float*)d_in[16];
  const float* ffW1 = (const float*)d_in[17];
  const float* ffb1 = (const float*)d_in[18];
  const float* ffW2 = (const float*)d_in[19];
  const float* ffb2 = (const float*)d_in[20];
  const float* maprojW = (const float*)d_in[21];
  const float* maprojb = (const float*)d_in[22];
  float* out = (float*)d_out;
  char* ws = (char*)d_ws;

  // Workspace (32.25 MB), time-disjoint aliasing:
  //  [0,4M)      A_proc f32 (dead after blk0 attn) / t1 bf16 [8192,256]
  //  [4,4.5)     A_offb   [4.5,5.5) A_pcing   [5.5,6.5) A_on     (f32)
  //  [6.5,8.5)   maCat bf16 [2048,512]
  //  [8.5,9.5)   k_buf bf16   [9.5,10.5) v_buf bf16
  //  [10.5,14.5) q_buf bf16 (dead after attn) / out1 bf16
  //  [14.5,22.5) ctx bf16 (dead after Wo-gemm) / ffh bf16 [8192,512]
  //  [22.5,26.5) ope_bf  [26.5,27.5) ma_bf  [27.5,28) veh_bf
  //  [28,28.5) WqT [28.5,29) WkT [29,29.5) WvT [29.5,30) WoT  (bf16, [4][256][256])
  //  [30,31) ffW1T [31,32) ffW2T [32,32.25) maprojT
  const size_t MB = 1 << 20;
  float* A_proc  = (float*)(ws + 0);
  u16*   t1      = (u16*)  (ws + 0);
  float* A_offb  = (float*)(ws + 4 * MB);
  float* A_pcing = (float*)(ws + 4 * MB + MB / 2);
  float* A_on    = (float*)(ws + 5 * MB + MB / 2);
  u16*   maCat   = (u16*)  (ws + 6 * MB + MB / 2);
  u16*   k_buf   = (u16*)  (ws + 8 * MB + MB / 2);
  u16*   v_buf   = (u16*)  (ws + 9 * MB + MB / 2);
  u16*   q_buf   = (u16*)  (ws + 10 * MB + MB / 2);
  u16*   out1    = (u16*)  (ws + 10 * MB + MB / 2);
  u16*   ctx_buf = (u16*)  (ws + 14 * MB + MB / 2);
  u16*   ffh     = (u16*)  (ws + 14 * MB + MB / 2);
  u16*   ope_bf  = (u16*)  (ws + 22 * MB + MB / 2);
  u16*   ma_bf   = (u16*)  (ws + 26 * MB + MB / 2);
  u16*   veh_bf  = (u16*)  (ws + 27 * MB + MB / 2);
  u16*   WqT     = (u16*)  (ws + 28 * MB);
  u16*   WkT     = (u16*)  (ws + 28 * MB + MB / 2);
  u16*   WvT     = (u16*)  (ws + 29 * MB);
  u16*   WoT     = (u16*)  (ws + 29 * MB + MB / 2);
  u16*   ffW1T   = (u16*)  (ws + 30 * MB);
  u16*   ffW2T   = (u16*)  (ws + 31 * MB);
  u16*   maprojT = (u16*)  (ws + 32 * MB);

  // one-time converts + weight transposes
  cvt_bf16<<<2048, 256, 0, stream>>>(ope, ope_bf, NBATCH * NOPE * EDIM / 4);
  cvt_bf16<<<512, 256, 0, stream>>>(ma, ma_bf, NBATCH * NMA * EDIM / 4);
  cvt_bf16<<<256, 256, 0, stream>>>(veh, veh_bf, NBATCH * NVEH * EDIM / 4);
  transpose_bf16<<<dim3(8, 8, 4), 256, 0, stream>>>(Wq, WqT, 256, 256);
  transpose_bf16<<<dim3(8, 8, 4), 256, 0, stream>>>(Wk, WkT, 256, 256);
  transpose_bf16<<<dim3(8, 8, 4), 256, 0, stream>>>(Wv, WvT, 256, 256);
  transpose_bf16<<<dim3(8, 8, 4), 256, 0, stream>>>(Wo, WoT, 256, 256);
  transpose_bf16<<<dim3(8, 16, 4), 256, 0, stream>>>(ffW1, ffW1T, 256, 512);
  transpose_bf16<<<dim3(16, 8, 4), 256, 0, stream>>>(ffW2, ffW2T, 512, 256);
  transpose_bf16<<<dim3(16, 8, 1), 256, 0, stream>>>(maprojW, maprojT, 512, 256);

  // adjacency
  aproc_kernel<<<NBATCH * NOPE, 128, 0, stream>>>(proc, mask_dyn, A_proc);
  aoff_kernel<<<NBATCH, 256, 0, stream>>>(mv, A_offb, NVEH * NMA);
  aon_kernel<<<NBATCH, 256, 0, stream>>>(trans, mask_ma, A_on, A_pcing);

  const size_t OPE_OUT = 0;
  const size_t MA_OUT  = (size_t)NBATCH * NOPE * EDIM;            // 2097152
  const size_t VEH_OUT = MA_OUT + (size_t)NBATCH * NMA * EDIM;    // 2621440

  auto run_block = [&](int i, const u16* row_bf, const float* row_f32, int M,
                       int R, const float* cost, float* dest_f, u16* dest_b,
                       int dstride, int doff) {
    gemm_mfma<u16><<<dim3(2, M / 128), 256, 0, stream>>>(row_bf,
        WqT + (size_t)i * 65536, nullptr, q_buf, M, 256, 256, 0);
    gemm_mfma<u16><<<dim3(2, 16), 256, 0, stream>>>(ma_bf,
        WkT + (size_t)i * 65536, nullptr, k_buf, 2048, 256, 256, 0);
    gemm_mfma<u16><<<dim3(2, 16), 256, 0, stream>>>(ma_bf,
        WvT + (size_t)i * 65536, nullptr, v_buf, 2048, 256, 256, 0);
    attn_kernel<<<M, 256, 0, stream>>>(q_buf, k_buf, v_buf, cost,
        mixW1 + (size_t)i * 256, mixb1 + (size_t)i * 128,
        mixW2 + (size_t)i * 128, mixb2 + (size_t)i * 16, ctx_buf, R);
    gemm_mfma<u16><<<dim3(2, M / 128), 256, 0, stream>>>(ctx_buf,
        WoT + (size_t)i * 65536, nullptr, t1, M, 256, 256, 0);
    ln_kernel<float, u16><<<M, 256, 0, stream>>>(row_f32, t1, out1, 256, 0);
    gemm_mfma<u16><<<dim3(4, M / 128), 256, 0, stream>>>(out1,
        ffW1T + (size_t)i * 131072, ffb1 + (size_t)i * 512, ffh, M, 512, 256, 2);
    gemm_mfma<u16><<<dim3(2, M / 128), 256, 0, stream>>>(ffh,
        ffW2T + (size_t)i * 131072, ffb2 + (size_t)i * 256, t1, M, 256, 512, 1);
    if (dest_f)
      ln_kernel<u16, float><<<M, 256, 0, stream>>>(out1, t1, dest_f, dstride, doff);
    else
      ln_kernel<u16, u16><<<M, 256, 0, stream>>>(out1, t1, dest_b, dstride, doff);
  };

  run_block(0, ope_bf, ope, NBATCH * NOPE, NOPE, A_proc,  out + OPE_OUT, nullptr, 256, 0);
  run_block(1, veh_bf, veh, NBATCH * NVEH, NVEH, A_offb,  out + VEH_OUT, nullptr, 256, 0);
  run_block(2, ma_bf,  ma,  NBATCH * NMA,  NMA,  A_pcing, nullptr, maCat, 512, 0);
  run_block(3, ma_bf,  ma,  NBATCH * NMA,  NMA,  A_on,    nullptr, maCat, 512, 256);

  // ma_out (f32) = concat(ma1, ma2) @ maprojW + maprojb
  gemm_mfma<float><<<dim3(2, 16), 256, 0, stream>>>(maCat, maprojT, maprojb,
      out + MA_OUT, 2048, 256, 512, 1);
}

// Round 6
// 587.676 us; speedup vs baseline: 1.7487x; 1.1833x over previous
//
#include <hip/hip_runtime.h>

// ---------------------------------------------------------------------------
// EncoderLayer (MatNet mixed-score MHA) for MI355X — R6: MFMA attention.
// B=16, NO=512, NM=128, NV=64, E=256, H=16, DK=16, MS=8, FF=512.
// Inputs f32, masks int32, d_out f32 (confirmed R4/R5).
// R6: attention rewritten as fused per-(b,rt16,head)-wave MFMA pipeline:
// QK^T (S^T layout, zero-padded K-depth) -> mix-MLP -> shuffle softmax ->
// P via LDS -> PV MFMA against transposed V. GEMMs unchanged from R5.
// ---------------------------------------------------------------------------

typedef unsigned short u16;
typedef __attribute__((ext_vector_type(8))) short bf16x8;
typedef __attribute__((ext_vector_type(4))) float f32x4;
struct us4 { u16 x, y, z, w; };

__device__ __forceinline__ float bf2f(u16 u) {
  return __uint_as_float(((unsigned int)u) << 16);
}
__device__ __forceinline__ u16 f2bf(float f) {
  unsigned int x = __float_as_uint(f);
  x += 0x7FFFu + ((x >> 16) & 1u);   // round-to-nearest-even
  return (u16)(x >> 16);
}
__device__ __forceinline__ float ldf(const float* p) { return *p; }
__device__ __forceinline__ float ldf(const u16* p) { return bf2f(*p); }
__device__ __forceinline__ void stf(float* p, float v) { *p = v; }
__device__ __forceinline__ void stf(u16* p, float v) { *p = f2bf(v); }

#define NBATCH 16
#define NOPE   512
#define NMA    128
#define NVEH   64
#define EDIM   256

// ---------------------------------------------------------------------------
// f32 -> bf16 elementwise convert (n % 4 == 0).
// ---------------------------------------------------------------------------
__global__ __launch_bounds__(256) void cvt_bf16(
    const float* __restrict__ src, u16* __restrict__ dst, int n4) {
  int i = blockIdx.x * 256 + threadIdx.x;
  if (i >= n4) return;
  float4 v = ((const float4*)src)[i];
  us4 o = { f2bf(v.x), f2bf(v.y), f2bf(v.z), f2bf(v.w) };
  ((us4*)dst)[i] = o;
}

// ---------------------------------------------------------------------------
// W [z][Kd][Nd] f32  ->  WT [z][Nd][Kd] bf16.  Kd,Nd % 32 == 0.
// ---------------------------------------------------------------------------
__global__ __launch_bounds__(256) void transpose_bf16(
    const float* __restrict__ src, u16* __restrict__ dst, int Kd, int Nd) {
  size_t zo = (size_t)blockIdx.z * Kd * Nd;
  src += zo; dst += zo;
  __shared__ float tile[32][33];
  int k0 = blockIdx.x * 32, n0 = blockIdx.y * 32;
  int tx = threadIdx.x & 31, ty = threadIdx.x >> 5;   // ty 0..7
#pragma unroll
  for (int r = 0; r < 4; r++)
    tile[ty + r * 8][tx] = src[(size_t)(k0 + ty + r * 8) * Nd + n0 + tx];
  __syncthreads();
#pragma unroll
  for (int r = 0; r < 4; r++)
    dst[(size_t)(n0 + ty + r * 8) * Kd + k0 + tx] = f2bf(tile[tx][ty + r * 8]);
}

// ---------------------------------------------------------------------------
// v_buf [16][128 c][256 d] bf16 -> vT [16][256 d][128 c] bf16.
// grid (8 d-tiles, 4 c-tiles, 16 b), 256 threads.
// ---------------------------------------------------------------------------
__global__ __launch_bounds__(256) void transpose_v(
    const u16* __restrict__ src, u16* __restrict__ dst) {
  int b = blockIdx.z;
  int d0 = blockIdx.x * 32, c0 = blockIdx.y * 32;
  __shared__ u16 tile[32][33];
  int tx = threadIdx.x & 31, ty = threadIdx.x >> 5;
  const u16* s = src + (size_t)b * 128 * 256;
  u16* d = dst + (size_t)b * 256 * 128;
#pragma unroll
  for (int r = 0; r < 4; r++)
    tile[ty + r * 8][tx] = s[(size_t)(c0 + ty + r * 8) * 256 + d0 + tx];
  __syncthreads();
#pragma unroll
  for (int r = 0; r < 4; r++)
    d[(size_t)(d0 + ty + r * 8) * 128 + c0 + tx] = tile[tx][ty + r * 8];
}

// ---------------------------------------------------------------------------
// Adjacency kernels (unchanged).
// ---------------------------------------------------------------------------
__global__ __launch_bounds__(128) void aproc_kernel(
    const float* __restrict__ proc, const int* __restrict__ mask,
    float* __restrict__ out) {
  int row = blockIdx.x;
  int t = threadIdx.x;
  size_t idx = (size_t)row * NMA + t;
  float a = mask[idx] ? proc[idx] : 0.0f;
  float cand = (a != 0.0f) ? a : 1.0e30f;
  __shared__ float red[128];
  red[t] = cand;
  __syncthreads();
  for (int s = 64; s > 0; s >>= 1) {
    if (t < s) red[t] = fminf(red[t], red[t + s]);
    __syncthreads();
  }
  float mn = red[0];
  out[idx] = (a != 0.0f && a == mn) ? 1.0f : 0.0f;
}

__global__ __launch_bounds__(256) void aoff_kernel(
    const float* __restrict__ x, float* __restrict__ out, int n) {
  int b = blockIdx.x, t = threadIdx.x;
  const float* xb = x + (size_t)b * n;
  float mn = 1.0e30f, mx = -1.0e30f;
  for (int i = t; i < n; i += 256) {
    float v = xb[i];
    mn = fminf(mn, v);
    mx = fmaxf(mx, v);
  }
  __shared__ float smn[256], smx[256];
  smn[t] = mn; smx[t] = mx;
  __syncthreads();
  for (int s = 128; s > 0; s >>= 1) {
    if (t < s) {
      smn[t] = fminf(smn[t], smn[t + s]);
      smx[t] = fmaxf(smx[t], smx[t + s]);
    }
    __syncthreads();
  }
  float lo = smn[0], hi = smx[0];
  float inv = 1.0f / (hi - lo);
  for (int i = t; i < n; i += 256)
    out[(size_t)b * n + i] = 1.0f - (xb[i] - lo) * inv;
}

__global__ __launch_bounds__(256) void aon_kernel(
    const float* __restrict__ trans, const int* __restrict__ mask_ma,
    float* __restrict__ a_on, float* __restrict__ a_pcing) {
  int b = blockIdx.x, t = threadIdx.x;
  __shared__ unsigned char mrow[NMA];
  if (t < NMA) mrow[t] = (unsigned char)(mask_ma[(size_t)b * NMA + t] != 0);
  __syncthreads();
  const float* tb = trans + (size_t)b * NMA * NMA;
  float mn = 1.0e30f, mx = -1.0e30f;
  for (int idx = t; idx < NMA * NMA; idx += 256) {
    int i = idx >> 7, j = idx & 127;
    bool m2 = mrow[i] && mrow[j];
    float tt = m2 ? tb[idx] : 101.0f;
    mn = fminf(mn, tt);
    mx = fmaxf(mx, tt);
  }
  __shared__ float smn[256], smx[256];
  smn[t] = mn; smx[t] = mx;
  __syncthreads();
  for (int s = 128; s > 0; s >>= 1) {
    if (t < s) {
      smn[t] = fminf(smn[t], smn[t + s]);
      smx[t] = fmaxf(smx[t], smx[t + s]);
    }
    __syncthreads();
  }
  float lo = smn[0], hi = smx[0];
  float inv = 1.0f / (hi - lo);
  for (int idx = t; idx < NMA * NMA; idx += 256) {
    int i = idx >> 7, j = idx & 127;
    bool m2 = mrow[i] && mrow[j];
    float tt = m2 ? tb[idx] : 101.0f;
    a_on[(size_t)b * NMA * NMA + idx] = 1.0f - (tt - lo) * inv;
    a_pcing[(size_t)b * NMA * NMA + idx] = m2 ? 0.0f : 1.0f;
  }
}

// ---------------------------------------------------------------------------
// MFMA GEMM (unchanged from R5): C[M,N] = A[M,K] @ WT[N,K]^T, bf16, f32 acc.
// ---------------------------------------------------------------------------
template <typename TO>
__global__ __launch_bounds__(256) void gemm_mfma(
    const u16* __restrict__ A, const u16* __restrict__ WT,
    const float* __restrict__ bias, TO* __restrict__ C,
    int M, int N, int K, int epi) {
  __shared__ u16 As[128][40];
  __shared__ u16 Bs[128][40];
  int tid = threadIdx.x;
  int lane = tid & 63, wid = tid >> 6;
  int wr = (wid >> 1) * 64, wc = (wid & 1) * 64;
  int m16 = lane & 15, quad = lane >> 4;
  int rb = blockIdx.y * 128, cb = blockIdx.x * 128;
  int srow = tid >> 2;
  int schunk = (tid & 3) * 8;

  f32x4 acc[4][4];
#pragma unroll
  for (int i = 0; i < 4; i++)
#pragma unroll
    for (int j = 0; j < 4; j++) acc[i][j] = (f32x4){0.f, 0.f, 0.f, 0.f};

  for (int k0 = 0; k0 < K; k0 += 32) {
    uint4 va0 = *(const uint4*)(A + (size_t)(rb + srow) * K + k0 + schunk);
    uint4 va1 = *(const uint4*)(A + (size_t)(rb + 64 + srow) * K + k0 + schunk);
    uint4 vb0 = *(const uint4*)(WT + (size_t)(cb + srow) * K + k0 + schunk);
    uint4 vb1 = *(const uint4*)(WT + (size_t)(cb + 64 + srow) * K + k0 + schunk);
    __syncthreads();
    *(uint4*)&As[srow][schunk] = va0;
    *(uint4*)&As[64 + srow][schunk] = va1;
    *(uint4*)&Bs[srow][schunk] = vb0;
    *(uint4*)&Bs[64 + srow][schunk] = vb1;
    __syncthreads();
    bf16x8 af[4], bfr[4];
#pragma unroll
    for (int i = 0; i < 4; i++)
      af[i] = *(const bf16x8*)&As[wr + i * 16 + m16][quad * 8];
#pragma unroll
    for (int j = 0; j < 4; j++)
      bfr[j] = *(const bf16x8*)&Bs[wc + j * 16 + m16][quad * 8];
#pragma unroll
    for (int i = 0; i < 4; i++)
#pragma unroll
      for (int j = 0; j < 4; j++)
        acc[i][j] = __builtin_amdgcn_mfma_f32_16x16x32_bf16(
            af[i], bfr[j], acc[i][j], 0, 0, 0);
  }

#pragma unroll
  for (int i = 0; i < 4; i++) {
#pragma unroll
    for (int j = 0; j < 4; j++) {
      int col = cb + wc + j * 16 + m16;
      float bv = (epi >= 1) ? bias[col] : 0.0f;
#pragma unroll
      for (int r = 0; r < 4; r++) {
        int row = rb + wr + i * 16 + quad * 4 + r;
        float v = acc[i][j][r] + bv;
        if (epi == 2) v = fmaxf(v, 0.0f);
        stf(&C[(size_t)row * N + col], v);
      }
    }
  }
}

// ---------------------------------------------------------------------------
// Fused MFMA attention. One wave per (b, 16-row tile, head).
// grid = (M/16)*4 blocks, 256 threads = 4 waves; wave w -> head (blk&3)*4+w.
// q,k: [*][256] bf16. vT: [b][256 d][128 c] bf16. cost: [M][128] f32.
// Per wave: S^T = K.Q^T via 8 zero-padded 16x16x32 MFMAs (lane: r=lane&15,
// c=ct*16+quad*4+reg) -> mix-MLP -> softmax over c (in-reg + shfl_xor 16/32)
// -> P to per-wave LDS (bf16, stride 136) -> PV via 4 MFMAs with vT B-frags.
// ---------------------------------------------------------------------------
__global__ __launch_bounds__(256) void attn_mfma(
    const u16* __restrict__ q, const u16* __restrict__ k,
    const u16* __restrict__ vT, const float* __restrict__ cost,
    const float* __restrict__ mixW1, const float* __restrict__ mixb1,
    const float* __restrict__ mixW2, const float* __restrict__ mixb2,
    u16* __restrict__ ctx, int R) {
  int t = threadIdx.x;
  int wave = t >> 6, lane = t & 63;
  int quad = lane >> 4, l16 = lane & 15;
  int hg = blockIdx.x & 3;
  int m0 = (blockIdx.x >> 2) * 16;        // global row base (16 rows, one b)
  int b = m0 / R;
  int h = hg * 4 + wave;

  __shared__ float costs[16 * 129];
  __shared__ u16 pbuf[4][16 * 136];

  // stage cost tile [16 r][128 c] (coalesced, conflict-free)
  const float* cp = cost + (size_t)m0 * 128;
  for (int i = t; i < 2048; i += 256) {
    costs[(i >> 7) * 129 + (i & 127)] = cp[i];
  }
  __syncthreads();

  // mix weights (wave-uniform)
  float w10[8], w11[8], wb1v[8], w2s[8];
#pragma unroll
  for (int s = 0; s < 8; s++) {
    w10[s] = mixW1[h * 16 + s];
    w11[s] = mixW1[h * 16 + 8 + s];
    wb1v[s] = mixb1[h * 8 + s];
    w2s[s] = mixW2[h * 8 + s];
  }
  float wb2v = mixb2[h];

  const bf16x8 zerof = (bf16x8){0, 0, 0, 0, 0, 0, 0, 0};
  const f32x4 zacc = (f32x4){0.f, 0.f, 0.f, 0.f};

  // B-frag: Q rows (n = r = l16, depth k = quad*8+j, zero-pad k>=16)
  bf16x8 bq = zerof;
  if (quad < 2)
    bq = *(const bf16x8*)(q + (size_t)(m0 + l16) * 256 + h * 16 + quad * 8);

  // S^T tiles: A-frag = K rows (m = c = ct*16+l16)
  f32x4 st[8];
#pragma unroll
  for (int ct = 0; ct < 8; ct++) {
    bf16x8 ak = zerof;
    if (quad < 2)
      ak = *(const bf16x8*)(k + (size_t)(b * 128 + ct * 16 + l16) * 256 +
                            h * 16 + quad * 8);
    st[ct] = __builtin_amdgcn_mfma_f32_16x16x32_bf16(ak, bq, zacc, 0, 0, 0);
  }

  // mix-MLP elementwise on scores; lane holds (r=l16, c=ct*16+quad*4+reg)
#pragma unroll
  for (int ct = 0; ct < 8; ct++) {
#pragma unroll
    for (int rg = 0; rg < 4; rg++) {
      float dot = st[ct][rg] * 0.25f;
      float co = costs[l16 * 129 + ct * 16 + quad * 4 + rg];
      float sv = wb2v;
#pragma unroll
      for (int s = 0; s < 8; s++)
        sv += fmaxf(dot * w10[s] + co * w11[s] + wb1v[s], 0.0f) * w2s[s];
      st[ct][rg] = sv;
    }
  }

  // softmax over c: 32 in-reg + cross-quad (lanes r, r+16, r+32, r+48)
  float mx = -1.0e30f;
#pragma unroll
  for (int ct = 0; ct < 8; ct++)
#pragma unroll
    for (int rg = 0; rg < 4; rg++) mx = fmaxf(mx, st[ct][rg]);
  mx = fmaxf(mx, __shfl_xor(mx, 16, 64));
  mx = fmaxf(mx, __shfl_xor(mx, 32, 64));
  float sum = 0.0f;
#pragma unroll
  for (int ct = 0; ct < 8; ct++)
#pragma unroll
    for (int rg = 0; rg < 4; rg++) {
      float e = __expf(st[ct][rg] - mx);
      st[ct][rg] = e;
      sum += e;
    }
  sum += __shfl_xor(sum, 16, 64);
  sum += __shfl_xor(sum, 32, 64);
  float inv = 1.0f / sum;

  // P -> LDS (bf16), rows r = l16, cols c
  u16* pb = pbuf[wave];
#pragma unroll
  for (int ct = 0; ct < 8; ct++) {
#pragma unroll
    for (int g = 0; g < 2; g++) {
      unsigned int pk = (unsigned int)f2bf(st[ct][g * 2] * inv) |
                        ((unsigned int)f2bf(st[ct][g * 2 + 1] * inv) << 16);
      *(unsigned int*)&pb[l16 * 136 + ct * 16 + quad * 4 + g * 2] = pk;
    }
  }

  // PV: D[m=r][n=dd] = sum_c P[r,c] * V[c, h*16+dd]; B-frag from vT rows.
  f32x4 cacc = zacc;
#pragma unroll
  for (int ks = 0; ks < 4; ks++) {
    bf16x8 ap = *(const bf16x8*)&pb[l16 * 136 + ks * 32 + quad * 8];
    bf16x8 bv = *(const bf16x8*)(vT + ((size_t)b * 256 + h * 16 + l16) * 128 +
                                 ks * 32 + quad * 8);
    cacc = __builtin_amdgcn_mfma_f32_16x16x32_bf16(ap, bv, cacc, 0, 0, 0);
  }

  // ctx store: row = m0 + quad*4 + reg, col = h*16 + l16
#pragma unroll
  for (int rg = 0; rg < 4; rg++)
    ctx[(size_t)(m0 + quad * 4 + rg) * 256 + h * 16 + l16] = f2bf(cacc[rg]);
}

// ---------------------------------------------------------------------------
// Residual + LayerNorm over E=256 (unchanged).
// ---------------------------------------------------------------------------
template <typename TR, typename TO>
__global__ __launch_bounds__(256) void ln_kernel(
    const TR* __restrict__ resid, const u16* __restrict__ x,
    TO* __restrict__ out, int ostride, int ooff) {
  int row = blockIdx.x, t = threadIdx.x;
  float vv = ldf(resid + (size_t)row * 256 + t) + bf2f(x[(size_t)row * 256 + t]);
  __shared__ float red[256];
  red[t] = vv;
  __syncthreads();
  for (int s = 128; s > 0; s >>= 1) {
    if (t < s) red[t] += red[t + s];
    __syncthreads();
  }
  float mean = red[0] * (1.0f / 256.0f);
  __syncthreads();
  float d = vv - mean;
  red[t] = d * d;
  __syncthreads();
  for (int s = 128; s > 0; s >>= 1) {
    if (t < s) red[t] += red[t + s];
    __syncthreads();
  }
  float var = red[0] * (1.0f / 256.0f);
  float y = d * rsqrtf(var + 1e-5f);
  stf(out + (size_t)row * ostride + ooff + t, y);
}

// ---------------------------------------------------------------------------
extern "C" void kernel_launch(void* const* d_in, const int* in_sizes, int n_in,
                              void* d_out, int out_size, void* d_ws, size_t ws_size,
                              hipStream_t stream) {
  const float* ope   = (const float*)d_in[0];
  const float* ma    = (const float*)d_in[1];
  const float* veh   = (const float*)d_in[2];
  const float* proc  = (const float*)d_in[3];
  const float* trans = (const float*)d_in[5];
  const float* mv    = (const float*)d_in[6];
  const int* mask_dyn = (const int*)d_in[7];
  const int* mask_ma  = (const int*)d_in[8];
  const float* Wq = (const float*)d_in[9];
  const float* Wk = (const float*)d_in[10];
  const float* Wv = (const float*)d_in[11];
  const float* Wo = (const float*)d_in[12];
  const float* mixW1 = (const float*)d_in[13];
  const float* mixb1 = (const float*)d_in[14];
  const float* mixW2 = (const float*)d_in[15];
  const float* mixb2 = (const float*)d_in[16];
  const float* ffW1 = (const float*)d_in[17];
  const float* ffb1 = (const float*)d_in[18];
  const float* ffW2 = (const float*)d_in[19];
  const float* ffb2 = (const float*)d_in[20];
  const float* maprojW = (const float*)d_in[21];
  const float* maprojb = (const float*)d_in[22];
  float* out = (float*)d_out;
  char* ws = (char*)d_ws;

  // Workspace (34 MB), time-disjoint aliasing (as R5) + vT at 33 MB:
  const size_t MB = 1 << 20;
  float* A_proc  = (float*)(ws + 0);
  u16*   t1      = (u16*)  (ws + 0);
  float* A_offb  = (float*)(ws + 4 * MB);
  float* A_pcing = (float*)(ws + 4 * MB + MB / 2);
  float* A_on    = (float*)(ws + 5 * MB + MB / 2);
  u16*   maCat   = (u16*)  (ws + 6 * MB + MB / 2);
  u16*   k_buf   = (u16*)  (ws + 8 * MB + MB / 2);
  u16*   v_buf   = (u16*)  (ws + 9 * MB + MB / 2);
  u16*   q_buf   = (u16*)  (ws + 10 * MB + MB / 2);
  u16*   out1    = (u16*)  (ws + 10 * MB + MB / 2);
  u16*   ctx_buf = (u16*)  (ws + 14 * MB + MB / 2);
  u16*   ffh     = (u16*)  (ws + 14 * MB + MB / 2);
  u16*   ope_bf  = (u16*)  (ws + 22 * MB + MB / 2);
  u16*   ma_bf   = (u16*)  (ws + 26 * MB + MB / 2);
  u16*   veh_bf  = (u16*)  (ws + 27 * MB + MB / 2);
  u16*   WqT     = (u16*)  (ws + 28 * MB);
  u16*   WkT     = (u16*)  (ws + 28 * MB + MB / 2);
  u16*   WvT     = (u16*)  (ws + 29 * MB);
  u16*   WoT     = (u16*)  (ws + 29 * MB + MB / 2);
  u16*   ffW1T   = (u16*)  (ws + 30 * MB);
  u16*   ffW2T   = (u16*)  (ws + 31 * MB);
  u16*   maprojT = (u16*)  (ws + 32 * MB);
  u16*   vT_buf  = (u16*)  (ws + 33 * MB);   // [16][256][128] bf16 = 1 MB

  // one-time converts + weight transposes
  cvt_bf16<<<2048, 256, 0, stream>>>(ope, ope_bf, NBATCH * NOPE * EDIM / 4);
  cvt_bf16<<<512, 256, 0, stream>>>(ma, ma_bf, NBATCH * NMA * EDIM / 4);
  cvt_bf16<<<256, 256, 0, stream>>>(veh, veh_bf, NBATCH * NVEH * EDIM / 4);
  transpose_bf16<<<dim3(8, 8, 4), 256, 0, stream>>>(Wq, WqT, 256, 256);
  transpose_bf16<<<dim3(8, 8, 4), 256, 0, stream>>>(Wk, WkT, 256, 256);
  transpose_bf16<<<dim3(8, 8, 4), 256, 0, stream>>>(Wv, WvT, 256, 256);
  transpose_bf16<<<dim3(8, 8, 4), 256, 0, stream>>>(Wo, WoT, 256, 256);
  transpose_bf16<<<dim3(8, 16, 4), 256, 0, stream>>>(ffW1, ffW1T, 256, 512);
  transpose_bf16<<<dim3(16, 8, 4), 256, 0, stream>>>(ffW2, ffW2T, 512, 256);
  transpose_bf16<<<dim3(16, 8, 1), 256, 0, stream>>>(maprojW, maprojT, 512, 256);

  // adjacency
  aproc_kernel<<<NBATCH * NOPE, 128, 0, stream>>>(proc, mask_dyn, A_proc);
  aoff_kernel<<<NBATCH, 256, 0, stream>>>(mv, A_offb, NVEH * NMA);
  aon_kernel<<<NBATCH, 256, 0, stream>>>(trans, mask_ma, A_on, A_pcing);

  const size_t OPE_OUT = 0;
  const size_t MA_OUT  = (size_t)NBATCH * NOPE * EDIM;            // 2097152
  const size_t VEH_OUT = MA_OUT + (size_t)NBATCH * NMA * EDIM;    // 2621440

  auto run_block = [&](int i, const u16* row_bf, const float* row_f32, int M,
                       int R, const float* cost, float* dest_f, u16* dest_b,
                       int dstride, int doff) {
    gemm_mfma<u16><<<dim3(2, M / 128), 256, 0, stream>>>(row_bf,
        WqT + (size_t)i * 65536, nullptr, q_buf, M, 256, 256, 0);
    gemm_mfma<u16><<<dim3(2, 16), 256, 0, stream>>>(ma_bf,
        WkT + (size_t)i * 65536, nullptr, k_buf, 2048, 256, 256, 0);
    gemm_mfma<u16><<<dim3(2, 16), 256, 0, stream>>>(ma_bf,
        WvT + (size_t)i * 65536, nullptr, v_buf, 2048, 256, 256, 0);
    transpose_v<<<dim3(8, 4, 16), 256, 0, stream>>>(v_buf, vT_buf);
    attn_mfma<<<(M / 16) * 4, 256, 0, stream>>>(q_buf, k_buf, vT_buf, cost,
        mixW1 + (size_t)i * 256, mixb1 + (size_t)i * 128,
        mixW2 + (size_t)i * 128, mixb2 + (size_t)i * 16, ctx_buf, R);
    gemm_mfma<u16><<<dim3(2, M / 128), 256, 0, stream>>>(ctx_buf,
        WoT + (size_t)i * 65536, nullptr, t1, M, 256, 256, 0);
    ln_kernel<float, u16><<<M, 256, 0, stream>>>(row_f32, t1, out1, 256, 0);
    gemm_mfma<u16><<<dim3(4, M / 128), 256, 0, stream>>>(out1,
        ffW1T + (size_t)i * 131072, ffb1 + (size_t)i * 512, ffh, M, 512, 256, 2);
    gemm_mfma<u16><<<dim3(2, M / 128), 256, 0, stream>>>(ffh,
        ffW2T + (size_t)i * 131072, ffb2 + (size_t)i * 256, t1, M, 256, 512, 1);
    if (dest_f)
      ln_kernel<u16, float><<<M, 256, 0, stream>>>(out1, t1, dest_f, dstride, doff);
    else
      ln_kernel<u16, u16><<<M, 256, 0, stream>>>(out1, t1, dest_b, dstride, doff);
  };

  run_block(0, ope_bf, ope, NBATCH * NOPE, NOPE, A_proc,  out + OPE_OUT, nullptr, 256, 0);
  run_block(1, veh_bf, veh, NBATCH * NVEH, NVEH, A_offb,  out + VEH_OUT, nullptr, 256, 0);
  run_block(2, ma_bf,  ma,  NBATCH * NMA,  NMA,  A_pcing, nullptr, maCat, 512, 0);
  run_block(3, ma_bf,  ma,  NBATCH * NMA,  NMA,  A_on,    nullptr, maCat, 512, 256);

  // ma_out (f32) = concat(ma1, ma2) @ maprojW + maprojb
  gemm_mfma<float><<<dim3(2, 16), 256, 0, stream>>>(maCat, maprojT, maprojb,
      out + MA_OUT, 2048, 256, 512, 1);
}

// Round 7
// 321.417 us; speedup vs baseline: 3.1973x; 1.8284x over previous
//
#include <hip/hip_runtime.h>

// ---------------------------------------------------------------------------
// EncoderLayer (MatNet mixed-score MHA) for MI355X — R7: grouped dispatches.
// B=16, NO=512, NM=128, NV=64, E=256, H=16, DK=16, MS=8, FF=512.
// Inputs f32, masks int32, d_out f32. The 4 encoder blocks are independent;
// all per-block stages are flattened into grouped kernels (15 dispatches).
// Row-space offsets: ope 0..8191, veh 8192..9215, ma1 9216..11263,
// ma2 11264..13311 (total 13312 rows).
// ---------------------------------------------------------------------------

typedef unsigned short u16;
typedef __attribute__((ext_vector_type(8))) short bf16x8;
typedef __attribute__((ext_vector_type(4))) float f32x4;
struct us4 { u16 x, y, z, w; };

__device__ __forceinline__ float bf2f(u16 u) {
  return __uint_as_float(((unsigned int)u) << 16);
}
__device__ __forceinline__ u16 f2bf(float f) {
  unsigned int x = __float_as_uint(f);
  x += 0x7FFFu + ((x >> 16) & 1u);
  return (u16)(x >> 16);
}

#define NBATCH 16
#define NOPE   512
#define NMA    128
#define NVEH   64
#define EDIM   256

// ---------------------------------------------------------------------------
// Grouped f32->bf16 convert: ope (n1), ma (n2-n1), veh (ntot-n2), float4.
// ---------------------------------------------------------------------------
__global__ __launch_bounds__(256) void cvt_grouped(
    const float* __restrict__ s0, const float* __restrict__ s1,
    const float* __restrict__ s2, u16* __restrict__ d0, u16* __restrict__ d1,
    u16* __restrict__ d2, int n1, int n2, int ntot) {
  int i = blockIdx.x * 256 + threadIdx.x;
  if (i >= ntot) return;
  const float* s; u16* d; int j;
  if (i < n1)      { s = s0; d = d0; j = i; }
  else if (i < n2) { s = s1; d = d1; j = i - n1; }
  else             { s = s2; d = d2; j = i - n2; }
  float4 v = ((const float4*)s)[j];
  us4 o = { f2bf(v.x), f2bf(v.y), f2bf(v.z), f2bf(v.w) };
  ((us4*)d)[j] = o;
}

// ---------------------------------------------------------------------------
// Generic f32 [Kd][Nd] -> bf16 [Nd][Kd] transpose (32x32 tiles).
// ---------------------------------------------------------------------------
__device__ __forceinline__ void tr_body(const float* src, u16* dst,
                                        int Kd, int Nd, int k0, int n0) {
  __shared__ float tile[32][33];
  int tx = threadIdx.x & 31, ty = threadIdx.x >> 5;
#pragma unroll
  for (int r = 0; r < 4; r++)
    tile[ty + r * 8][tx] = src[(size_t)(k0 + ty + r * 8) * Nd + n0 + tx];
  __syncthreads();
#pragma unroll
  for (int r = 0; r < 4; r++)
    dst[(size_t)(n0 + ty + r * 8) * Kd + k0 + tx] = f2bf(tile[tx][ty + r * 8]);
}

__global__ __launch_bounds__(256) void transpose_bf16(
    const float* __restrict__ src, u16* __restrict__ dst, int Kd, int Nd) {
  size_t zo = (size_t)blockIdx.z * Kd * Nd;
  tr_body(src + zo, dst + zo, Kd, Nd, blockIdx.x * 32, blockIdx.y * 32);
}

// 4 weights x 4 blocks of 256x256: z = w*4+i, w in {q,k,v,o}.
__global__ __launch_bounds__(256) void transpose_w4(
    const float* __restrict__ sq, const float* __restrict__ sk,
    const float* __restrict__ sv, const float* __restrict__ so,
    u16* __restrict__ dq, u16* __restrict__ dk,
    u16* __restrict__ dv, u16* __restrict__ d_o) {
  int w = blockIdx.z >> 2, i = blockIdx.z & 3;
  const float* s = (w == 0 ? sq : w == 1 ? sk : w == 2 ? sv : so) +
                   (size_t)i * 65536;
  u16* d = (w == 0 ? dq : w == 1 ? dk : w == 2 ? dv : d_o) + (size_t)i * 65536;
  tr_body(s, d, 256, 256, blockIdx.x * 32, blockIdx.y * 32);
}

// ffW2 (4 blocks) + maproj, all 512x256: z<4 -> ffW2[z], z==4 -> maproj.
__global__ __launch_bounds__(256) void transpose_b5(
    const float* __restrict__ sf, const float* __restrict__ sm,
    u16* __restrict__ df, u16* __restrict__ dm) {
  int z = blockIdx.z;
  const float* s = (z < 4) ? sf + (size_t)z * 131072 : sm;
  u16* d = (z < 4) ? df + (size_t)z * 131072 : dm;
  tr_body(s, d, 512, 256, blockIdx.x * 32, blockIdx.y * 32);
}

// ---------------------------------------------------------------------------
// v_all [4][16 b][128 c][256 d] -> vT_all [4][16 b][256 d][128 c], bf16.
// grid (8 d-tiles, 4 c-tiles, 64): z -> g=z>>4, b=z&15.
// ---------------------------------------------------------------------------
__global__ __launch_bounds__(256) void transpose_v(
    const u16* __restrict__ src, u16* __restrict__ dst) {
  int g = blockIdx.z >> 4, b = blockIdx.z & 15;
  int d0 = blockIdx.x * 32, c0 = blockIdx.y * 32;
  __shared__ u16 tile[32][33];
  int tx = threadIdx.x & 31, ty = threadIdx.x >> 5;
  const u16* s = src + ((size_t)g * 16 + b) * 32768;
  u16* d = dst + ((size_t)g * 16 + b) * 32768;
#pragma unroll
  for (int r = 0; r < 4; r++)
    tile[ty + r * 8][tx] = s[(size_t)(c0 + ty + r * 8) * 256 + d0 + tx];
  __syncthreads();
#pragma unroll
  for (int r = 0; r < 4; r++)
    d[(size_t)(d0 + ty + r * 8) * 128 + c0 + tx] = tile[tx][ty + r * 8];
}

// ---------------------------------------------------------------------------
// Adjacency kernels (unchanged).
// ---------------------------------------------------------------------------
__global__ __launch_bounds__(128) void aproc_kernel(
    const float* __restrict__ proc, const int* __restrict__ mask,
    float* __restrict__ out) {
  int row = blockIdx.x;
  int t = threadIdx.x;
  size_t idx = (size_t)row * NMA + t;
  float a = mask[idx] ? proc[idx] : 0.0f;
  float cand = (a != 0.0f) ? a : 1.0e30f;
  __shared__ float red[128];
  red[t] = cand;
  __syncthreads();
  for (int s = 64; s > 0; s >>= 1) {
    if (t < s) red[t] = fminf(red[t], red[t + s]);
    __syncthreads();
  }
  float mn = red[0];
  out[idx] = (a != 0.0f && a == mn) ? 1.0f : 0.0f;
}

__global__ __launch_bounds__(256) void aoff_kernel(
    const float* __restrict__ x, float* __restrict__ out, int n) {
  int b = blockIdx.x, t = threadIdx.x;
  const float* xb = x + (size_t)b * n;
  float mn = 1.0e30f, mx = -1.0e30f;
  for (int i = t; i < n; i += 256) {
    float v = xb[i];
    mn = fminf(mn, v);
    mx = fmaxf(mx, v);
  }
  __shared__ float smn[256], smx[256];
  smn[t] = mn; smx[t] = mx;
  __syncthreads();
  for (int s = 128; s > 0; s >>= 1) {
    if (t < s) {
      smn[t] = fminf(smn[t], smn[t + s]);
      smx[t] = fmaxf(smx[t], smx[t + s]);
    }
    __syncthreads();
  }
  float lo = smn[0], hi = smx[0];
  float inv = 1.0f / (hi - lo);
  for (int i = t; i < n; i += 256)
    out[(size_t)b * n + i] = 1.0f - (xb[i] - lo) * inv;
}

__global__ __launch_bounds__(256) void aon_kernel(
    const float* __restrict__ trans, const int* __restrict__ mask_ma,
    float* __restrict__ a_on, float* __restrict__ a_pcing) {
  int b = blockIdx.x, t = threadIdx.x;
  __shared__ unsigned char mrow[NMA];
  if (t < NMA) mrow[t] = (unsigned char)(mask_ma[(size_t)b * NMA + t] != 0);
  __syncthreads();
  const float* tb = trans + (size_t)b * NMA * NMA;
  float mn = 1.0e30f, mx = -1.0e30f;
  for (int idx = t; idx < NMA * NMA; idx += 256) {
    int i = idx >> 7, j = idx & 127;
    bool m2 = mrow[i] && mrow[j];
    float tt = m2 ? tb[idx] : 101.0f;
    mn = fminf(mn, tt);
    mx = fmaxf(mx, tt);
  }
  __shared__ float smn[256], smx[256];
  smn[t] = mn; smx[t] = mx;
  __syncthreads();
  for (int s = 128; s > 0; s >>= 1) {
    if (t < s) {
      smn[t] = fminf(smn[t], smn[t + s]);
      smx[t] = fmaxf(smx[t], smx[t + s]);
    }
    __syncthreads();
  }
  float lo = smn[0], hi = smx[0];
  float inv = 1.0f / (hi - lo);
  for (int idx = t; idx < NMA * NMA; idx += 256) {
    int i = idx >> 7, j = idx & 127;
    bool m2 = mrow[i] && mrow[j];
    float tt = m2 ? tb[idx] : 101.0f;
    a_on[(size_t)b * NMA * NMA + idx] = 1.0f - (tt - lo) * inv;
    a_pcing[(size_t)b * NMA * NMA + idx] = m2 ? 0.0f : 1.0f;
  }
}

// ---------------------------------------------------------------------------
// Grouped MFMA GEMM: per-group C[M,N] = A[M,K] @ WT[N,K]^T (+bias)(+relu).
// Descriptor table by value; group resolved from blockIdx.x (wave-uniform).
// 128x128 tile, 4 waves, 16x16x32 bf16 MFMA, f32 acc, bf16 C.
// ---------------------------------------------------------------------------
struct GG {
  const u16* A; const u16* WT; const float* bias; u16* C;
  int M, N, K, epi, wgStart, wgCols;
};
struct GGArgs { GG g[12]; int n; };

__global__ __launch_bounds__(256) void gemm_grouped(GGArgs args) {
  int wg = blockIdx.x;
  int gi = 0;
  for (int i = 1; i < args.n; i++)
    if (wg >= args.g[i].wgStart) gi = i;
  GG gg = args.g[gi];
  int lwg = wg - gg.wgStart;
  int bx = lwg & (gg.wgCols - 1);
  int by = lwg >> ((gg.wgCols == 2) ? 1 : 2);
  int N = gg.N, K = gg.K;

  __shared__ u16 As[128][40];
  __shared__ u16 Bs[128][40];
  int tid = threadIdx.x;
  int lane = tid & 63, wid = tid >> 6;
  int wr = (wid >> 1) * 64, wc = (wid & 1) * 64;
  int m16 = lane & 15, quad = lane >> 4;
  int rb = by * 128, cb = bx * 128;
  int srow = tid >> 2;
  int schunk = (tid & 3) * 8;

  f32x4 acc[4][4];
#pragma unroll
  for (int i = 0; i < 4; i++)
#pragma unroll
    for (int j = 0; j < 4; j++) acc[i][j] = (f32x4){0.f, 0.f, 0.f, 0.f};

  for (int k0 = 0; k0 < K; k0 += 32) {
    uint4 va0 = *(const uint4*)(gg.A + (size_t)(rb + srow) * K + k0 + schunk);
    uint4 va1 = *(const uint4*)(gg.A + (size_t)(rb + 64 + srow) * K + k0 + schunk);
    uint4 vb0 = *(const uint4*)(gg.WT + (size_t)(cb + srow) * K + k0 + schunk);
    uint4 vb1 = *(const uint4*)(gg.WT + (size_t)(cb + 64 + srow) * K + k0 + schunk);
    __syncthreads();
    *(uint4*)&As[srow][schunk] = va0;
    *(uint4*)&As[64 + srow][schunk] = va1;
    *(uint4*)&Bs[srow][schunk] = vb0;
    *(uint4*)&Bs[64 + srow][schunk] = vb1;
    __syncthreads();
    bf16x8 af[4], bfr[4];
#pragma unroll
    for (int i = 0; i < 4; i++)
      af[i] = *(const bf16x8*)&As[wr + i * 16 + m16][quad * 8];
#pragma unroll
    for (int j = 0; j < 4; j++)
      bfr[j] = *(const bf16x8*)&Bs[wc + j * 16 + m16][quad * 8];
#pragma unroll
    for (int i = 0; i < 4; i++)
#pragma unroll
      for (int j = 0; j < 4; j++)
        acc[i][j] = __builtin_amdgcn_mfma_f32_16x16x32_bf16(
            af[i], bfr[j], acc[i][j], 0, 0, 0);
  }

#pragma unroll
  for (int i = 0; i < 4; i++) {
#pragma unroll
    for (int j = 0; j < 4; j++) {
      int col = cb + wc + j * 16 + m16;
      float bv = (gg.epi >= 1) ? gg.bias[col] : 0.0f;
#pragma unroll
      for (int r = 0; r < 4; r++) {
        int row = rb + wr + i * 16 + quad * 4 + r;
        float v = acc[i][j][r] + bv;
        if (gg.epi == 2) v = fmaxf(v, 0.0f);
        gg.C[(size_t)row * N + col] = f2bf(v);
      }
    }
  }
}

// ---------------------------------------------------------------------------
// Plain MFMA GEMM with f32 output (final ma-projection only).
// ---------------------------------------------------------------------------
__global__ __launch_bounds__(256) void gemm_mfma_f32(
    const u16* __restrict__ A, const u16* __restrict__ WT,
    const float* __restrict__ bias, float* __restrict__ C,
    int M, int N, int K) {
  __shared__ u16 As[128][40];
  __shared__ u16 Bs[128][40];
  int tid = threadIdx.x;
  int lane = tid & 63, wid = tid >> 6;
  int wr = (wid >> 1) * 64, wc = (wid & 1) * 64;
  int m16 = lane & 15, quad = lane >> 4;
  int rb = blockIdx.y * 128, cb = blockIdx.x * 128;
  int srow = tid >> 2;
  int schunk = (tid & 3) * 8;
  f32x4 acc[4][4];
#pragma unroll
  for (int i = 0; i < 4; i++)
#pragma unroll
    for (int j = 0; j < 4; j++) acc[i][j] = (f32x4){0.f, 0.f, 0.f, 0.f};
  for (int k0 = 0; k0 < K; k0 += 32) {
    uint4 va0 = *(const uint4*)(A + (size_t)(rb + srow) * K + k0 + schunk);
    uint4 va1 = *(const uint4*)(A + (size_t)(rb + 64 + srow) * K + k0 + schunk);
    uint4 vb0 = *(const uint4*)(WT + (size_t)(cb + srow) * K + k0 + schunk);
    uint4 vb1 = *(const uint4*)(WT + (size_t)(cb + 64 + srow) * K + k0 + schunk);
    __syncthreads();
    *(uint4*)&As[srow][schunk] = va0;
    *(uint4*)&As[64 + srow][schunk] = va1;
    *(uint4*)&Bs[srow][schunk] = vb0;
    *(uint4*)&Bs[64 + srow][schunk] = vb1;
    __syncthreads();
    bf16x8 af[4], bfr[4];
#pragma unroll
    for (int i = 0; i < 4; i++)
      af[i] = *(const bf16x8*)&As[wr + i * 16 + m16][quad * 8];
#pragma unroll
    for (int j = 0; j < 4; j++)
      bfr[j] = *(const bf16x8*)&Bs[wc + j * 16 + m16][quad * 8];
#pragma unroll
    for (int i = 0; i < 4; i++)
#pragma unroll
      for (int j = 0; j < 4; j++)
        acc[i][j] = __builtin_amdgcn_mfma_f32_16x16x32_bf16(
            af[i], bfr[j], acc[i][j], 0, 0, 0);
  }
#pragma unroll
  for (int i = 0; i < 4; i++)
#pragma unroll
    for (int j = 0; j < 4; j++) {
      int col = cb + wc + j * 16 + m16;
      float bv = bias[col];
#pragma unroll
      for (int r = 0; r < 4; r++) {
        int row = rb + wr + i * 16 + quad * 4 + r;
        C[(size_t)row * N + col] = acc[i][j][r] + bv;
      }
    }
}

// ---------------------------------------------------------------------------
// Grouped fused MFMA attention (R6 structure, 4 groups in one dispatch).
// ---------------------------------------------------------------------------
struct AG {
  const u16* q; const u16* k; const u16* vT; const float* cost; u16* ctx;
  const float* w1; const float* b1; const float* w2; const float* b2;
  int R, wgStart;
};
struct AGArgs { AG g[4]; };

__global__ __launch_bounds__(256) void attn_grouped(AGArgs args) {
  int blk = blockIdx.x;
  int gi = 0;
#pragma unroll
  for (int i = 1; i < 4; i++)
    if (blk >= args.g[i].wgStart) gi = i;
  AG gg = args.g[gi];
  int local = blk - gg.wgStart;

  int t = threadIdx.x;
  int wave = t >> 6, lane = t & 63;
  int quad = lane >> 4, l16 = lane & 15;
  int hg = local & 3;
  int m0 = (local >> 2) * 16;
  int b = m0 / gg.R;
  int h = hg * 4 + wave;

  __shared__ float costs[16 * 129];
  __shared__ u16 pbuf[4][16 * 136];

  const float* cp = gg.cost + (size_t)m0 * 128;
  for (int i = t; i < 2048; i += 256)
    costs[(i >> 7) * 129 + (i & 127)] = cp[i];
  __syncthreads();

  float w10[8], w11[8], wb1v[8], w2s[8];
#pragma unroll
  for (int s = 0; s < 8; s++) {
    w10[s] = gg.w1[h * 16 + s];
    w11[s] = gg.w1[h * 16 + 8 + s];
    wb1v[s] = gg.b1[h * 8 + s];
    w2s[s] = gg.w2[h * 8 + s];
  }
  float wb2v = gg.b2[h];

  const bf16x8 zerof = (bf16x8){0, 0, 0, 0, 0, 0, 0, 0};
  const f32x4 zacc = (f32x4){0.f, 0.f, 0.f, 0.f};

  bf16x8 bq = zerof;
  if (quad < 2)
    bq = *(const bf16x8*)(gg.q + (size_t)(m0 + l16) * 256 + h * 16 + quad * 8);

  f32x4 st[8];
#pragma unroll
  for (int ct = 0; ct < 8; ct++) {
    bf16x8 ak = zerof;
    if (quad < 2)
      ak = *(const bf16x8*)(gg.k + (size_t)(b * 128 + ct * 16 + l16) * 256 +
                            h * 16 + quad * 8);
    st[ct] = __builtin_amdgcn_mfma_f32_16x16x32_bf16(ak, bq, zacc, 0, 0, 0);
  }

#pragma unroll
  for (int ct = 0; ct < 8; ct++) {
#pragma unroll
    for (int rg = 0; rg < 4; rg++) {
      float dot = st[ct][rg] * 0.25f;
      float co = costs[l16 * 129 + ct * 16 + quad * 4 + rg];
      float sv = wb2v;
#pragma unroll
      for (int s = 0; s < 8; s++)
        sv += fmaxf(dot * w10[s] + co * w11[s] + wb1v[s], 0.0f) * w2s[s];
      st[ct][rg] = sv;
    }
  }

  float mx = -1.0e30f;
#pragma unroll
  for (int ct = 0; ct < 8; ct++)
#pragma unroll
    for (int rg = 0; rg < 4; rg++) mx = fmaxf(mx, st[ct][rg]);
  mx = fmaxf(mx, __shfl_xor(mx, 16, 64));
  mx = fmaxf(mx, __shfl_xor(mx, 32, 64));
  float sum = 0.0f;
#pragma unroll
  for (int ct = 0; ct < 8; ct++)
#pragma unroll
    for (int rg = 0; rg < 4; rg++) {
      float e = __expf(st[ct][rg] - mx);
      st[ct][rg] = e;
      sum += e;
    }
  sum += __shfl_xor(sum, 16, 64);
  sum += __shfl_xor(sum, 32, 64);
  float inv = 1.0f / sum;

  u16* pb = pbuf[wave];
#pragma unroll
  for (int ct = 0; ct < 8; ct++) {
#pragma unroll
    for (int g2 = 0; g2 < 2; g2++) {
      unsigned int pk = (unsigned int)f2bf(st[ct][g2 * 2] * inv) |
                        ((unsigned int)f2bf(st[ct][g2 * 2 + 1] * inv) << 16);
      *(unsigned int*)&pb[l16 * 136 + ct * 16 + quad * 4 + g2 * 2] = pk;
    }
  }

  f32x4 cacc = zacc;
#pragma unroll
  for (int ks = 0; ks < 4; ks++) {
    bf16x8 ap = *(const bf16x8*)&pb[l16 * 136 + ks * 32 + quad * 8];
    bf16x8 bv = *(const bf16x8*)(gg.vT + (size_t)b * 32768 +
                                 (size_t)(h * 16 + l16) * 128 + ks * 32 + quad * 8);
    cacc = __builtin_amdgcn_mfma_f32_16x16x32_bf16(ap, bv, cacc, 0, 0, 0);
  }

#pragma unroll
  for (int rg = 0; rg < 4; rg++)
    gg.ctx[(size_t)(m0 + quad * 4 + rg) * 256 + h * 16 + l16] = f2bf(cacc[rg]);
}

// ---------------------------------------------------------------------------
// Grouped LN1: out1[row] = LN(resid_g[row-local] + t1[row]); resid f32.
// ---------------------------------------------------------------------------
struct LN1Args {
  const float* r0; const float* r1; const float* r2; const float* r3;
  int s1, s2, s3;
};
__global__ __launch_bounds__(256) void ln1_grouped(
    LN1Args a, const u16* __restrict__ x, u16* __restrict__ out) {
  int row = blockIdx.x, t = threadIdx.x;
  const float* resid;
  int local;
  if (row < a.s1)      { resid = a.r0; local = row; }
  else if (row < a.s2) { resid = a.r1; local = row - a.s1; }
  else if (row < a.s3) { resid = a.r2; local = row - a.s2; }
  else                 { resid = a.r3; local = row - a.s3; }
  float vv = resid[(size_t)local * 256 + t] + bf2f(x[(size_t)row * 256 + t]);
  __shared__ float red[256];
  red[t] = vv;
  __syncthreads();
  for (int s = 128; s > 0; s >>= 1) {
    if (t < s) red[t] += red[t + s];
    __syncthreads();
  }
  float mean = red[0] * (1.0f / 256.0f);
  __syncthreads();
  float d = vv - mean;
  red[t] = d * d;
  __syncthreads();
  for (int s = 128; s > 0; s >>= 1) {
    if (t < s) red[t] += red[t + s];
    __syncthreads();
  }
  float var = red[0] * (1.0f / 256.0f);
  out[(size_t)row * 256 + t] = f2bf(d * rsqrtf(var + 1e-5f));
}

// ---------------------------------------------------------------------------
// Grouped LN2: dst varies per group (f32 d_out or bf16 maCat w/ stride 512).
// ---------------------------------------------------------------------------
struct LN2Args {
  float* f0; float* f1; u16* b2; u16* b3;
  int s1, s2, s3;
};
__global__ __launch_bounds__(256) void ln2_grouped(
    LN2Args a, const u16* __restrict__ resid, const u16* __restrict__ x) {
  int row = blockIdx.x, t = threadIdx.x;
  float vv = bf2f(resid[(size_t)row * 256 + t]) + bf2f(x[(size_t)row * 256 + t]);
  __shared__ float red[256];
  red[t] = vv;
  __syncthreads();
  for (int s = 128; s > 0; s >>= 1) {
    if (t < s) red[t] += red[t + s];
    __syncthreads();
  }
  float mean = red[0] * (1.0f / 256.0f);
  __syncthreads();
  float d = vv - mean;
  red[t] = d * d;
  __syncthreads();
  for (int s = 128; s > 0; s >>= 1) {
    if (t < s) red[t] += red[t + s];
    __syncthreads();
  }
  float var = red[0] * (1.0f / 256.0f);
  float y = d * rsqrtf(var + 1e-5f);
  if (row < a.s1)
    a.f0[(size_t)row * 256 + t] = y;
  else if (row < a.s2)
    a.f1[(size_t)(row - a.s1) * 256 + t] = y;
  else if (row < a.s3)
    a.b2[(size_t)(row - a.s2) * 512 + t] = f2bf(y);
  else
    a.b3[(size_t)(row - a.s3) * 512 + 256 + t] = f2bf(y);
}

// ---------------------------------------------------------------------------
extern "C" void kernel_launch(void* const* d_in, const int* in_sizes, int n_in,
                              void* d_out, int out_size, void* d_ws, size_t ws_size,
                              hipStream_t stream) {
  const float* ope   = (const float*)d_in[0];
  const float* ma    = (const float*)d_in[1];
  const float* veh   = (const float*)d_in[2];
  const float* proc  = (const float*)d_in[3];
  const float* trans = (const float*)d_in[5];
  const float* mv    = (const float*)d_in[6];
  const int* mask_dyn = (const int*)d_in[7];
  const int* mask_ma  = (const int*)d_in[8];
  const float* Wq = (const float*)d_in[9];
  const float* Wk = (const float*)d_in[10];
  const float* Wv = (const float*)d_in[11];
  const float* Wo = (const float*)d_in[12];
  const float* mixW1 = (const float*)d_in[13];
  const float* mixb1 = (const float*)d_in[14];
  const float* mixW2 = (const float*)d_in[15];
  const float* mixb2 = (const float*)d_in[16];
  const float* ffW1 = (const float*)d_in[17];
  const float* ffb1 = (const float*)d_in[18];
  const float* ffW2 = (const float*)d_in[19];
  const float* ffb2 = (const float*)d_in[20];
  const float* maprojW = (const float*)d_in[21];
  const float* maprojb = (const float*)d_in[22];
  float* out = (float*)d_out;
  char* ws = (char*)d_ws;

  // Row-space: ope [0,8192), veh [8192,9216), ma1 [9216,11264), ma2 [11264,13312)
  const int OFF[4] = {0, 8192, 9216, 11264};
  const int MS4[4] = {8192, 1024, 2048, 2048};
  const int TOT = 13312;

  // Workspace (~69.5 MB, no aliasing):
  const size_t MB = 1 << 20;
  float* A_proc  = (float*)(ws + 0);                 // [8192][128] 4 MB
  float* A_offb  = (float*)(ws + 4 * MB);            // [1024][128] .5 MB
  float* A_pcing = (float*)(ws + 4 * MB + MB / 2);   // 1 MB
  float* A_on    = (float*)(ws + 5 * MB + MB / 2);   // 1 MB
  u16* ope_bf  = (u16*)(ws + 6 * MB + MB / 2);       // 4 MB
  u16* ma_bf   = (u16*)(ws + 10 * MB + MB / 2);      // 1 MB
  u16* veh_bf  = (u16*)(ws + 11 * MB + MB / 2);      // .5 MB
  u16* WqT     = (u16*)(ws + 12 * MB);               // .5 MB each
  u16* WkT     = (u16*)(ws + 12 * MB + MB / 2);
  u16* WvT     = (u16*)(ws + 13 * MB);
  u16* WoT     = (u16*)(ws + 13 * MB + MB / 2);
  u16* ffW1T   = (u16*)(ws + 14 * MB);               // 1 MB
  u16* ffW2T   = (u16*)(ws + 15 * MB);               // 1 MB
  u16* maprojT = (u16*)(ws + 16 * MB);               // .25 MB
  u16* q_all   = (u16*)(ws + 16 * MB + MB / 2);      // [13312][256] 6.5 MB
  u16* k_all   = (u16*)(ws + 23 * MB);               // [4][2048][256] 4 MB
  u16* v_all   = (u16*)(ws + 27 * MB);               // 4 MB
  u16* vT_all  = (u16*)(ws + 31 * MB);               // 4 MB
  u16* ctx_all = (u16*)(ws + 35 * MB);               // 6.5 MB
  u16* t1_all  = (u16*)(ws + 41 * MB + MB / 2);      // 6.5 MB
  u16* out1_all= (u16*)(ws + 48 * MB);               // 6.5 MB
  u16* ffh_all = (u16*)(ws + 54 * MB + MB / 2);      // [13312][512] 13 MB
  u16* maCat   = (u16*)(ws + 67 * MB + MB / 2);      // [2048][512] 2 MB

  // --- converts & transposes (4 dispatches) ---
  cvt_grouped<<<2816, 256, 0, stream>>>(ope, ma, veh, ope_bf, ma_bf, veh_bf,
      524288, 655360, 720896);
  transpose_w4<<<dim3(8, 8, 16), 256, 0, stream>>>(Wq, Wk, Wv, Wo,
      WqT, WkT, WvT, WoT);
  transpose_bf16<<<dim3(8, 16, 4), 256, 0, stream>>>(ffW1, ffW1T, 256, 512);
  transpose_b5<<<dim3(16, 8, 5), 256, 0, stream>>>(ffW2, maprojW, ffW2T, maprojT);

  // --- adjacency (3 dispatches) ---
  aproc_kernel<<<NBATCH * NOPE, 128, 0, stream>>>(proc, mask_dyn, A_proc);
  aoff_kernel<<<NBATCH, 256, 0, stream>>>(mv, A_offb, NVEH * NMA);
  aon_kernel<<<NBATCH, 256, 0, stream>>>(trans, mask_ma, A_on, A_pcing);

  const size_t MA_OUT  = (size_t)NBATCH * NOPE * EDIM;            // 2097152
  const size_t VEH_OUT = MA_OUT + (size_t)NBATCH * NMA * EDIM;    // 2621440

  const u16* rowbf[4] = {ope_bf, veh_bf, ma_bf, ma_bf};
  const float* costp[4] = {A_proc, A_offb, A_pcing, A_on};

  // --- grouped GEMM #1: q (x4) + k (x4) + v (x4) ---
  {
    GGArgs ga; ga.n = 12;
    int wg = 0;
    for (int i = 0; i < 4; i++) {   // q
      ga.g[i] = {rowbf[i], WqT + (size_t)i * 65536, nullptr,
                 q_all + (size_t)OFF[i] * 256, MS4[i], 256, 256, 0, wg, 2};
      wg += (MS4[i] / 128) * 2;
    }
    for (int i = 0; i < 4; i++) {   // k
      ga.g[4 + i] = {ma_bf, WkT + (size_t)i * 65536, nullptr,
                     k_all + (size_t)i * 524288, 2048, 256, 256, 0, wg, 2};
      wg += 32;
    }
    for (int i = 0; i < 4; i++) {   // v
      ga.g[8 + i] = {ma_bf, WvT + (size_t)i * 65536, nullptr,
                     v_all + (size_t)i * 524288, 2048, 256, 256, 0, wg, 2};
      wg += 32;
    }
    gemm_grouped<<<wg, 256, 0, stream>>>(ga);   // 464 wg
  }

  transpose_v<<<dim3(8, 4, 64), 256, 0, stream>>>(v_all, vT_all);

  // --- grouped attention ---
  {
    AGArgs aa;
    int wg = 0;
    const int R4[4] = {NOPE, NVEH, NMA, NMA};
    for (int i = 0; i < 4; i++) {
      aa.g[i] = {q_all + (size_t)OFF[i] * 256, k_all + (size_t)i * 524288,
                 vT_all + (size_t)i * 524288, costp[i],
                 ctx_all + (size_t)OFF[i] * 256,
                 mixW1 + (size_t)i * 256, mixb1 + (size_t)i * 128,
                 mixW2 + (size_t)i * 128, mixb2 + (size_t)i * 16,
                 R4[i], wg};
      wg += (MS4[i] / 16) * 4;
    }
    attn_grouped<<<wg, 256, 0, stream>>>(aa);   // 3328 wg
  }

  // --- grouped GEMM #2: Wo ---
  {
    GGArgs ga; ga.n = 4;
    int wg = 0;
    for (int i = 0; i < 4; i++) {
      ga.g[i] = {ctx_all + (size_t)OFF[i] * 256, WoT + (size_t)i * 65536,
                 nullptr, t1_all + (size_t)OFF[i] * 256,
                 MS4[i], 256, 256, 0, wg, 2};
      wg += (MS4[i] / 128) * 2;
    }
    gemm_grouped<<<wg, 256, 0, stream>>>(ga);   // 208 wg
  }

  // --- LN1 ---
  {
    LN1Args la = {ope, veh, ma, ma, 8192, 9216, 11264};
    ln1_grouped<<<TOT, 256, 0, stream>>>(la, t1_all, out1_all);
  }

  // --- grouped GEMM #3: FF1 (bias+relu) ---
  {
    GGArgs ga; ga.n = 4;
    int wg = 0;
    for (int i = 0; i < 4; i++) {
      ga.g[i] = {out1_all + (size_t)OFF[i] * 256, ffW1T + (size_t)i * 131072,
                 ffb1 + (size_t)i * 512, ffh_all + (size_t)OFF[i] * 512,
                 MS4[i], 512, 256, 2, wg, 4};
      wg += (MS4[i] / 128) * 4;
    }
    gemm_grouped<<<wg, 256, 0, stream>>>(ga);   // 416 wg
  }

  // --- grouped GEMM #4: FF2 (bias) ---
  {
    GGArgs ga; ga.n = 4;
    int wg = 0;
    for (int i = 0; i < 4; i++) {
      ga.g[i] = {ffh_all + (size_t)OFF[i] * 512, ffW2T + (size_t)i * 131072,
                 ffb2 + (size_t)i * 256, t1_all + (size_t)OFF[i] * 256,
                 MS4[i], 256, 512, 1, wg, 2};
      wg += (MS4[i] / 128) * 2;
    }
    gemm_grouped<<<wg, 256, 0, stream>>>(ga);   // 208 wg
  }

  // --- LN2 (writes ope/veh f32 outputs + maCat halves) ---
  {
    LN2Args la = {out, out + VEH_OUT, maCat, maCat, 8192, 9216, 11264};
    ln2_grouped<<<TOT, 256, 0, stream>>>(la, out1_all, t1_all);
  }

  // --- final ma projection (f32 out) ---
  gemm_mfma_f32<<<dim3(2, 16), 256, 0, stream>>>(maCat, maprojT, maprojb,
      out + MA_OUT, 2048, 256, 512);
}

// Round 10
// 299.890 us; speedup vs baseline: 3.4268x; 1.0718x over previous
//
#include <hip/hip_runtime.h>
#include <hip/hip_fp16.h>
#include <hip/hip_bf16.h>

// ---------------------------------------------------------------------------
// EncoderLayer (MatNet mixed-score MHA) for MI355X — R10 (= R8 + fp16-max
// fix: ROCm 7.2 has no __half2 __hmax2 overload; use v_pk_max_f16 asm).
// attn = 1 block/16-row-tile, 16 heads (4/wave), fp16-packed mix-MLP,
// bf16-pair packed P; 11 dispatches total.
// Inputs f32, masks int32, d_out f32. Row-space: ope[0,8192) veh[8192,9216)
// ma1[9216,11264) ma2[11264,13312).
// ---------------------------------------------------------------------------

typedef unsigned short u16;
typedef __attribute__((ext_vector_type(8))) short bf16x8;
typedef __attribute__((ext_vector_type(4))) float f32x4;
struct us4 { u16 x, y, z, w; };

__device__ __forceinline__ float bf2f(u16 u) {
  return __uint_as_float(((unsigned int)u) << 16);
}
__device__ __forceinline__ u16 f2bf(float f) {
  unsigned int x = __float_as_uint(f);
  x += 0x7FFFu + ((x >> 16) & 1u);
  return (u16)(x >> 16);
}
// packed fp16 max (ROCm 7.2 lacks the __half2 __hmax2 overload on gfx950)
__device__ __forceinline__ __half2 h2max(__half2 a, __half2 b) {
  unsigned au = *(unsigned*)&a, bu = *(unsigned*)&b, ru;
  asm("v_pk_max_f16 %0, %1, %2" : "=v"(ru) : "v"(au), "v"(bu));
  return *(__half2*)&ru;
}

#define NBATCH 16
#define NOPE   512
#define NMA    128
#define NVEH   64
#define EDIM   256

// ---------------------------------------------------------------------------
// Grouped prep: [0,2816) f32->bf16 converts; [2816,6912) aproc (2 rows/blk);
// [6912,6928) aoff; [6928,6944) aon.
// ---------------------------------------------------------------------------
struct PrepArgs {
  const float* ope; const float* ma; const float* veh;
  u16* ope_bf; u16* ma_bf; u16* veh_bf;
  const float* proc; const int* mask_dyn; float* A_proc;
  const float* mv; float* A_offb;
  const float* trans; const int* mask_ma; float* A_on; float* A_pcing;
};
__global__ __launch_bounds__(256) void prep_grouped(PrepArgs a) {
  int blk = blockIdx.x, t = threadIdx.x;
  if (blk < 2816) {
    int i = blk * 256 + t;
    const float* s; u16* d; int j;
    if (i < 524288)      { s = a.ope; d = a.ope_bf; j = i; }
    else if (i < 655360) { s = a.ma;  d = a.ma_bf;  j = i - 524288; }
    else                 { s = a.veh; d = a.veh_bf; j = i - 655360; }
    float4 v = ((const float4*)s)[j];
    us4 o = { f2bf(v.x), f2bf(v.y), f2bf(v.z), f2bf(v.w) };
    ((us4*)d)[j] = o;
    return;
  }
  if (blk < 6912) {
    int local = blk - 2816;
    int row = local * 2 + (t >> 7);
    int lane = t & 127;
    size_t idx = (size_t)row * NMA + lane;
    float av = a.mask_dyn[idx] ? a.proc[idx] : 0.0f;
    float cand = (av != 0.0f) ? av : 1.0e30f;
    __shared__ float red[256];
    red[t] = cand;
    __syncthreads();
    for (int s = 64; s > 0; s >>= 1) {
      if (lane < s) red[t] = fminf(red[t], red[t + s]);
      __syncthreads();
    }
    float mn = red[t & 128];
    a.A_proc[idx] = (av != 0.0f && av == mn) ? 1.0f : 0.0f;
    return;
  }
  if (blk < 6928) {
    int b = blk - 6912;
    const int n = NVEH * NMA;
    const float* xb = a.mv + (size_t)b * n;
    float mn = 1.0e30f, mx = -1.0e30f;
    for (int i = t; i < n; i += 256) {
      float v = xb[i];
      mn = fminf(mn, v);
      mx = fmaxf(mx, v);
    }
    __shared__ float smn[256], smx[256];
    smn[t] = mn; smx[t] = mx;
    __syncthreads();
    for (int s = 128; s > 0; s >>= 1) {
      if (t < s) {
        smn[t] = fminf(smn[t], smn[t + s]);
        smx[t] = fmaxf(smx[t], smx[t + s]);
      }
      __syncthreads();
    }
    float lo = smn[0], inv = 1.0f / (smx[0] - smn[0]);
    for (int i = t; i < n; i += 256)
      a.A_offb[(size_t)b * n + i] = 1.0f - (xb[i] - lo) * inv;
    return;
  }
  {
    int b = blk - 6928;
    __shared__ unsigned char mrow[NMA];
    if (t < NMA) mrow[t] = (unsigned char)(a.mask_ma[(size_t)b * NMA + t] != 0);
    __syncthreads();
    const float* tb = a.trans + (size_t)b * NMA * NMA;
    float mn = 1.0e30f, mx = -1.0e30f;
    for (int idx = t; idx < NMA * NMA; idx += 256) {
      int i = idx >> 7, j = idx & 127;
      bool m2 = mrow[i] && mrow[j];
      float tt = m2 ? tb[idx] : 101.0f;
      mn = fminf(mn, tt);
      mx = fmaxf(mx, tt);
    }
    __shared__ float smn[256], smx[256];
    smn[t] = mn; smx[t] = mx;
    __syncthreads();
    for (int s = 128; s > 0; s >>= 1) {
      if (t < s) {
        smn[t] = fminf(smn[t], smn[t + s]);
        smx[t] = fmaxf(smx[t], smx[t + s]);
      }
      __syncthreads();
    }
    float lo = smn[0], inv = 1.0f / (smx[0] - smn[0]);
    for (int idx = t; idx < NMA * NMA; idx += 256) {
      int i = idx >> 7, j = idx & 127;
      bool m2 = mrow[i] && mrow[j];
      float tt = m2 ? tb[idx] : 101.0f;
      a.A_on[(size_t)b * NMA * NMA + idx] = 1.0f - (tt - lo) * inv;
      a.A_pcing[(size_t)b * NMA * NMA + idx] = m2 ? 0.0f : 1.0f;
    }
  }
}

// ---------------------------------------------------------------------------
// Merged weight transposes: f32 [Kd][Nd] -> bf16 [Nd][Kd], 32x32 tiles.
// ---------------------------------------------------------------------------
struct TrArgs {
  const float* Wq; const float* Wk; const float* Wv; const float* Wo;
  const float* ffW1; const float* ffW2; const float* maproj;
  u16* WqT; u16* WkT; u16* WvT; u16* WoT; u16* ffW1T; u16* ffW2T; u16* maprojT;
};
__global__ __launch_bounds__(256) void transpose_all(TrArgs a) {
  int blk = blockIdx.x;
  const float* src; u16* dst; int Kd, Nd, tile;
  if (blk < 1024) {
    int w = blk >> 8, i = (blk >> 6) & 3; tile = blk & 63;
    const float* sw = (w == 0 ? a.Wq : w == 1 ? a.Wk : w == 2 ? a.Wv : a.Wo);
    u16* dw = (w == 0 ? a.WqT : w == 1 ? a.WkT : w == 2 ? a.WvT : a.WoT);
    src = sw + (size_t)i * 65536; dst = dw + (size_t)i * 65536;
    Kd = 256; Nd = 256;
  } else if (blk < 1536) {
    int z = (blk - 1024) >> 7; tile = (blk - 1024) & 127;
    src = a.ffW1 + (size_t)z * 131072; dst = a.ffW1T + (size_t)z * 131072;
    Kd = 256; Nd = 512;
  } else {
    int z = (blk - 1536) >> 7; tile = (blk - 1536) & 127;
    if (z < 4) { src = a.ffW2 + (size_t)z * 131072; dst = a.ffW2T + (size_t)z * 131072; }
    else       { src = a.maproj; dst = a.maprojT; }
    Kd = 512; Nd = 256;
  }
  int nx = Nd >> 5;
  int k0 = (tile / nx) * 32, n0 = (tile % nx) * 32;
  __shared__ float tl[32][33];
  int tx = threadIdx.x & 31, ty = threadIdx.x >> 5;
#pragma unroll
  for (int r = 0; r < 4; r++)
    tl[ty + r * 8][tx] = src[(size_t)(k0 + ty + r * 8) * Nd + n0 + tx];
  __syncthreads();
#pragma unroll
  for (int r = 0; r < 4; r++)
    dst[(size_t)(n0 + ty + r * 8) * Kd + k0 + tx] = f2bf(tl[tx][ty + r * 8]);
}

// ---------------------------------------------------------------------------
// v_all [4][16 b][128 c][256 d] -> vT_all [4][16 b][256 d][128 c], bf16.
// ---------------------------------------------------------------------------
__global__ __launch_bounds__(256) void transpose_v(
    const u16* __restrict__ src, u16* __restrict__ dst) {
  int g = blockIdx.z >> 4, b = blockIdx.z & 15;
  int d0 = blockIdx.x * 32, c0 = blockIdx.y * 32;
  __shared__ u16 tile[32][33];
  int tx = threadIdx.x & 31, ty = threadIdx.x >> 5;
  const u16* s = src + ((size_t)g * 16 + b) * 32768;
  u16* d = dst + ((size_t)g * 16 + b) * 32768;
#pragma unroll
  for (int r = 0; r < 4; r++)
    tile[ty + r * 8][tx] = s[(size_t)(c0 + ty + r * 8) * 256 + d0 + tx];
  __syncthreads();
#pragma unroll
  for (int r = 0; r < 4; r++)
    d[(size_t)(d0 + ty + r * 8) * 128 + c0 + tx] = tile[tx][ty + r * 8];
}

// ---------------------------------------------------------------------------
// Grouped MFMA GEMM.
// ---------------------------------------------------------------------------
struct GG {
  const u16* A; const u16* WT; const float* bias; u16* C;
  int M, N, K, epi, wgStart, wgCols;
};
struct GGArgs { GG g[12]; int n; };

__global__ __launch_bounds__(256) void gemm_grouped(GGArgs args) {
  int wg = blockIdx.x;
  int gi = 0;
  for (int i = 1; i < args.n; i++)
    if (wg >= args.g[i].wgStart) gi = i;
  GG gg = args.g[gi];
  int lwg = wg - gg.wgStart;
  int bx = lwg & (gg.wgCols - 1);
  int by = lwg >> ((gg.wgCols == 2) ? 1 : 2);
  int N = gg.N, K = gg.K;

  __shared__ u16 As[128][40];
  __shared__ u16 Bs[128][40];
  int tid = threadIdx.x;
  int lane = tid & 63, wid = tid >> 6;
  int wr = (wid >> 1) * 64, wc = (wid & 1) * 64;
  int m16 = lane & 15, quad = lane >> 4;
  int rb = by * 128, cb = bx * 128;
  int srow = tid >> 2;
  int schunk = (tid & 3) * 8;

  f32x4 acc[4][4];
#pragma unroll
  for (int i = 0; i < 4; i++)
#pragma unroll
    for (int j = 0; j < 4; j++) acc[i][j] = (f32x4){0.f, 0.f, 0.f, 0.f};

  for (int k0 = 0; k0 < K; k0 += 32) {
    uint4 va0 = *(const uint4*)(gg.A + (size_t)(rb + srow) * K + k0 + schunk);
    uint4 va1 = *(const uint4*)(gg.A + (size_t)(rb + 64 + srow) * K + k0 + schunk);
    uint4 vb0 = *(const uint4*)(gg.WT + (size_t)(cb + srow) * K + k0 + schunk);
    uint4 vb1 = *(const uint4*)(gg.WT + (size_t)(cb + 64 + srow) * K + k0 + schunk);
    __syncthreads();
    *(uint4*)&As[srow][schunk] = va0;
    *(uint4*)&As[64 + srow][schunk] = va1;
    *(uint4*)&Bs[srow][schunk] = vb0;
    *(uint4*)&Bs[64 + srow][schunk] = vb1;
    __syncthreads();
    bf16x8 af[4], bfr[4];
#pragma unroll
    for (int i = 0; i < 4; i++)
      af[i] = *(const bf16x8*)&As[wr + i * 16 + m16][quad * 8];
#pragma unroll
    for (int j = 0; j < 4; j++)
      bfr[j] = *(const bf16x8*)&Bs[wc + j * 16 + m16][quad * 8];
#pragma unroll
    for (int i = 0; i < 4; i++)
#pragma unroll
      for (int j = 0; j < 4; j++)
        acc[i][j] = __builtin_amdgcn_mfma_f32_16x16x32_bf16(
            af[i], bfr[j], acc[i][j], 0, 0, 0);
  }

#pragma unroll
  for (int i = 0; i < 4; i++) {
#pragma unroll
    for (int j = 0; j < 4; j++) {
      int col = cb + wc + j * 16 + m16;
      float bv = (gg.epi >= 1) ? gg.bias[col] : 0.0f;
#pragma unroll
      for (int r = 0; r < 4; r++) {
        int row = rb + wr + i * 16 + quad * 4 + r;
        float v = acc[i][j][r] + bv;
        if (gg.epi == 2) v = fmaxf(v, 0.0f);
        gg.C[(size_t)row * N + col] = f2bf(v);
      }
    }
  }
}

// ---------------------------------------------------------------------------
// Plain MFMA GEMM with f32 output (final ma-projection).
// ---------------------------------------------------------------------------
__global__ __launch_bounds__(256) void gemm_mfma_f32(
    const u16* __restrict__ A, const u16* __restrict__ WT,
    const float* __restrict__ bias, float* __restrict__ C,
    int M, int N, int K) {
  __shared__ u16 As[128][40];
  __shared__ u16 Bs[128][40];
  int tid = threadIdx.x;
  int lane = tid & 63, wid = tid >> 6;
  int wr = (wid >> 1) * 64, wc = (wid & 1) * 64;
  int m16 = lane & 15, quad = lane >> 4;
  int rb = blockIdx.y * 128, cb = blockIdx.x * 128;
  int srow = tid >> 2;
  int schunk = (tid & 3) * 8;
  f32x4 acc[4][4];
#pragma unroll
  for (int i = 0; i < 4; i++)
#pragma unroll
    for (int j = 0; j < 4; j++) acc[i][j] = (f32x4){0.f, 0.f, 0.f, 0.f};
  for (int k0 = 0; k0 < K; k0 += 32) {
    uint4 va0 = *(const uint4*)(A + (size_t)(rb + srow) * K + k0 + schunk);
    uint4 va1 = *(const uint4*)(A + (size_t)(rb + 64 + srow) * K + k0 + schunk);
    uint4 vb0 = *(const uint4*)(WT + (size_t)(cb + srow) * K + k0 + schunk);
    uint4 vb1 = *(const uint4*)(WT + (size_t)(cb + 64 + srow) * K + k0 + schunk);
    __syncthreads();
    *(uint4*)&As[srow][schunk] = va0;
    *(uint4*)&As[64 + srow][schunk] = va1;
    *(uint4*)&Bs[srow][schunk] = vb0;
    *(uint4*)&Bs[64 + srow][schunk] = vb1;
    __syncthreads();
    bf16x8 af[4], bfr[4];
#pragma unroll
    for (int i = 0; i < 4; i++)
      af[i] = *(const bf16x8*)&As[wr + i * 16 + m16][quad * 8];
#pragma unroll
    for (int j = 0; j < 4; j++)
      bfr[j] = *(const bf16x8*)&Bs[wc + j * 16 + m16][quad * 8];
#pragma unroll
    for (int i = 0; i < 4; i++)
#pragma unroll
      for (int j = 0; j < 4; j++)
        acc[i][j] = __builtin_amdgcn_mfma_f32_16x16x32_bf16(
            af[i], bfr[j], acc[i][j], 0, 0, 0);
  }
#pragma unroll
  for (int i = 0; i < 4; i++)
#pragma unroll
    for (int j = 0; j < 4; j++) {
      int col = cb + wc + j * 16 + m16;
      float bv = bias[col];
#pragma unroll
      for (int r = 0; r < 4; r++) {
        int row = rb + wr + i * 16 + quad * 4 + r;
        C[(size_t)row * N + col] = acc[i][j][r] + bv;
      }
    }
}

// ---------------------------------------------------------------------------
// Grouped fused MFMA attention: one block per 16-row tile, all 16 heads
// (wave w -> heads w*4..w*4+3 sequential). Cost staged once as fp16.
// Mix-MLP in packed fp16 (__hfma2 + v_pk_max_f16); 0.25 folded into w10.
// ---------------------------------------------------------------------------
struct AG {
  const u16* q; const u16* k; const u16* vT; const float* cost; u16* ctx;
  const float* w1; const float* b1; const float* w2; const float* b2;
  int R, wgStart;
};
struct AGArgs { AG g[4]; };

#define CSTRIDE 134   // halves; <=2-way LDS banks on half2 reads

__global__ __launch_bounds__(256) void attn_grouped(AGArgs args) {
  int blk = blockIdx.x;
  int gi = 0;
#pragma unroll
  for (int i = 1; i < 4; i++)
    if (blk >= args.g[i].wgStart) gi = i;
  AG gg = args.g[gi];
  int local = blk - gg.wgStart;

  int t = threadIdx.x;
  int wave = t >> 6, lane = t & 63;
  int quad = lane >> 4, l16 = lane & 15;
  int m0 = local * 16;
  int b = m0 / gg.R;

  __shared__ __half costs_h[16 * CSTRIDE];
  __shared__ u16 pbuf[4][16 * 136];

  const float* cp = gg.cost + (size_t)m0 * 128;
  for (int i = t; i < 2048; i += 256)
    costs_h[(i >> 7) * CSTRIDE + (i & 127)] = __float2half(cp[i]);
  __syncthreads();

  const bf16x8 zerof = (bf16x8){0, 0, 0, 0, 0, 0, 0, 0};
  const f32x4 zacc = (f32x4){0.f, 0.f, 0.f, 0.f};
  const __half2 zh = __float2half2_rn(0.0f);
  u16* pb = pbuf[wave];

  for (int hh = 0; hh < 4; hh++) {
    int h = wave * 4 + hh;

    // wave-uniform mix weights (scalar loads); fold 0.25 into w10
    __half2 w10h[8], w11h[8], b1h[8], w2h[8];
#pragma unroll
    for (int s = 0; s < 8; s++) {
      w10h[s] = __float2half2_rn(gg.w1[h * 16 + s] * 0.25f);
      w11h[s] = __float2half2_rn(gg.w1[h * 16 + 8 + s]);
      b1h[s]  = __float2half2_rn(gg.b1[h * 8 + s]);
      w2h[s]  = __float2half2_rn(gg.w2[h * 8 + s]);
    }
    float wb2v = gg.b2[h];

    // QK^T (S^T layout): A = K rows, B = Q rows, zero-padded depth
    bf16x8 bq = zerof;
    if (quad < 2)
      bq = *(const bf16x8*)(gg.q + (size_t)(m0 + l16) * 256 + h * 16 + quad * 8);
    f32x4 st[8];
#pragma unroll
    for (int ct = 0; ct < 8; ct++) {
      bf16x8 ak = zerof;
      if (quad < 2)
        ak = *(const bf16x8*)(gg.k + (size_t)(b * 128 + ct * 16 + l16) * 256 +
                              h * 16 + quad * 8);
      st[ct] = __builtin_amdgcn_mfma_f32_16x16x32_bf16(ak, bq, zacc, 0, 0, 0);
    }

    // mix-MLP, packed fp16 on (rg, rg+1) pairs
#pragma unroll
    for (int ct = 0; ct < 8; ct++) {
#pragma unroll
      for (int p = 0; p < 2; p++) {
        __half2 d2 = __float22half2_rn(
            make_float2(st[ct][p * 2], st[ct][p * 2 + 1]));
        __half2 c2 = *(const __half2*)&costs_h[l16 * CSTRIDE + ct * 16 +
                                               quad * 4 + p * 2];
        __half2 s2 = zh;
#pragma unroll
        for (int s = 0; s < 8; s++) {
          __half2 hm = __hfma2(d2, w10h[s], __hfma2(c2, w11h[s], b1h[s]));
          hm = h2max(hm, zh);
          s2 = __hfma2(hm, w2h[s], s2);
        }
        float2 sf = __half22float2(s2);
        st[ct][p * 2]     = sf.x + wb2v;
        st[ct][p * 2 + 1] = sf.y + wb2v;
      }
    }

    // softmax over c (32 in-reg + cross-quad shuffles)
    float mx = -1.0e30f;
#pragma unroll
    for (int ct = 0; ct < 8; ct++)
#pragma unroll
      for (int rg = 0; rg < 4; rg++) mx = fmaxf(mx, st[ct][rg]);
    mx = fmaxf(mx, __shfl_xor(mx, 16, 64));
    mx = fmaxf(mx, __shfl_xor(mx, 32, 64));
    float sum = 0.0f;
#pragma unroll
    for (int ct = 0; ct < 8; ct++)
#pragma unroll
      for (int rg = 0; rg < 4; rg++) {
        float e = __expf(st[ct][rg] - mx);
        st[ct][rg] = e;
        sum += e;
      }
    sum += __shfl_xor(sum, 16, 64);
    sum += __shfl_xor(sum, 32, 64);
    float inv = 1.0f / sum;

    // P -> per-wave LDS as packed bf16 pairs
#pragma unroll
    for (int ct = 0; ct < 8; ct++) {
#pragma unroll
      for (int p = 0; p < 2; p++) {
        __hip_bfloat162 pk = __float22bfloat162_rn(
            make_float2(st[ct][p * 2] * inv, st[ct][p * 2 + 1] * inv));
        *(unsigned int*)&pb[l16 * 136 + ct * 16 + quad * 4 + p * 2] =
            *(unsigned int*)&pk;
      }
    }

    // PV: B-frags from vT rows (contiguous 16B)
    f32x4 cacc = zacc;
#pragma unroll
    for (int ks = 0; ks < 4; ks++) {
      bf16x8 ap = *(const bf16x8*)&pb[l16 * 136 + ks * 32 + quad * 8];
      bf16x8 bv = *(const bf16x8*)(gg.vT + (size_t)b * 32768 +
                                   (size_t)(h * 16 + l16) * 128 + ks * 32 +
                                   quad * 8);
      cacc = __builtin_amdgcn_mfma_f32_16x16x32_bf16(ap, bv, cacc, 0, 0, 0);
    }

#pragma unroll
    for (int rg = 0; rg < 4; rg++)
      gg.ctx[(size_t)(m0 + quad * 4 + rg) * 256 + h * 16 + l16] =
          f2bf(cacc[rg]);
  }
}

// ---------------------------------------------------------------------------
// Grouped LN1 / LN2.
// ---------------------------------------------------------------------------
struct LN1Args {
  const float* r0; const float* r1; const float* r2; const float* r3;
  int s1, s2, s3;
};
__global__ __launch_bounds__(256) void ln1_grouped(
    LN1Args a, const u16* __restrict__ x, u16* __restrict__ out) {
  int row = blockIdx.x, t = threadIdx.x;
  const float* resid;
  int local;
  if (row < a.s1)      { resid = a.r0; local = row; }
  else if (row < a.s2) { resid = a.r1; local = row - a.s1; }
  else if (row < a.s3) { resid = a.r2; local = row - a.s2; }
  else                 { resid = a.r3; local = row - a.s3; }
  float vv = resid[(size_t)local * 256 + t] + bf2f(x[(size_t)row * 256 + t]);
  __shared__ float red[256];
  red[t] = vv;
  __syncthreads();
  for (int s = 128; s > 0; s >>= 1) {
    if (t < s) red[t] += red[t + s];
    __syncthreads();
  }
  float mean = red[0] * (1.0f / 256.0f);
  __syncthreads();
  float d = vv - mean;
  red[t] = d * d;
  __syncthreads();
  for (int s = 128; s > 0; s >>= 1) {
    if (t < s) red[t] += red[t + s];
    __syncthreads();
  }
  float var = red[0] * (1.0f / 256.0f);
  out[(size_t)row * 256 + t] = f2bf(d * rsqrtf(var + 1e-5f));
}

struct LN2Args {
  float* f0; float* f1; u16* b2; u16* b3;
  int s1, s2, s3;
};
__global__ __launch_bounds__(256) void ln2_grouped(
    LN2Args a, const u16* __restrict__ resid, const u16* __restrict__ x) {
  int row = blockIdx.x, t = threadIdx.x;
  float vv = bf2f(resid[(size_t)row * 256 + t]) + bf2f(x[(size_t)row * 256 + t]);
  __shared__ float red[256];
  red[t] = vv;
  __syncthreads();
  for (int s = 128; s > 0; s >>= 1) {
    if (t < s) red[t] += red[t + s];
    __syncthreads();
  }
  float mean = red[0] * (1.0f / 256.0f);
  __syncthreads();
  float d = vv - mean;
  red[t] = d * d;
  __syncthreads();
  for (int s = 128; s > 0; s >>= 1) {
    if (t < s) red[t] += red[t + s];
    __syncthreads();
  }
  float var = red[0] * (1.0f / 256.0f);
  float y = d * rsqrtf(var + 1e-5f);
  if (row < a.s1)
    a.f0[(size_t)row * 256 + t] = y;
  else if (row < a.s2)
    a.f1[(size_t)(row - a.s1) * 256 + t] = y;
  else if (row < a.s3)
    a.b2[(size_t)(row - a.s2) * 512 + t] = f2bf(y);
  else
    a.b3[(size_t)(row - a.s3) * 512 + 256 + t] = f2bf(y);
}

// ---------------------------------------------------------------------------
extern "C" void kernel_launch(void* const* d_in, const int* in_sizes, int n_in,
                              void* d_out, int out_size, void* d_ws, size_t ws_size,
                              hipStream_t stream) {
  const float* ope   = (const float*)d_in[0];
  const float* ma    = (const float*)d_in[1];
  const float* veh   = (const float*)d_in[2];
  const float* proc  = (const float*)d_in[3];
  const float* trans = (const float*)d_in[5];
  const float* mv    = (const float*)d_in[6];
  const int* mask_dyn = (const int*)d_in[7];
  const int* mask_ma  = (const int*)d_in[8];
  const float* Wq = (const float*)d_in[9];
  const float* Wk = (const float*)d_in[10];
  const float* Wv = (const float*)d_in[11];
  const float* Wo = (const float*)d_in[12];
  const float* mixW1 = (const float*)d_in[13];
  const float* mixb1 = (const float*)d_in[14];
  const float* mixW2 = (const float*)d_in[15];
  const float* mixb2 = (const float*)d_in[16];
  const float* ffW1 = (const float*)d_in[17];
  const float* ffb1 = (const float*)d_in[18];
  const float* ffW2 = (const float*)d_in[19];
  const float* ffb2 = (const float*)d_in[20];
  const float* maprojW = (const float*)d_in[21];
  const float* maprojb = (const float*)d_in[22];
  float* out = (float*)d_out;
  char* ws = (char*)d_ws;

  const int OFF[4] = {0, 8192, 9216, 11264};
  const int MS4[4] = {8192, 1024, 2048, 2048};
  const int TOT = 13312;

  const size_t MB = 1 << 20;
  float* A_proc  = (float*)(ws + 0);
  float* A_offb  = (float*)(ws + 4 * MB);
  float* A_pcing = (float*)(ws + 4 * MB + MB / 2);
  float* A_on    = (float*)(ws + 5 * MB + MB / 2);
  u16* ope_bf  = (u16*)(ws + 6 * MB + MB / 2);
  u16* ma_bf   = (u16*)(ws + 10 * MB + MB / 2);
  u16* veh_bf  = (u16*)(ws + 11 * MB + MB / 2);
  u16* WqT     = (u16*)(ws + 12 * MB);
  u16* WkT     = (u16*)(ws + 12 * MB + MB / 2);
  u16* WvT     = (u16*)(ws + 13 * MB);
  u16* WoT     = (u16*)(ws + 13 * MB + MB / 2);
  u16* ffW1T   = (u16*)(ws + 14 * MB);
  u16* ffW2T   = (u16*)(ws + 15 * MB);
  u16* maprojT = (u16*)(ws + 16 * MB);
  u16* q_all   = (u16*)(ws + 16 * MB + MB / 2);
  u16* k_all   = (u16*)(ws + 23 * MB);
  u16* v_all   = (u16*)(ws + 27 * MB);
  u16* vT_all  = (u16*)(ws + 31 * MB);
  u16* ctx_all = (u16*)(ws + 35 * MB);
  u16* t1_all  = (u16*)(ws + 41 * MB + MB / 2);
  u16* out1_all= (u16*)(ws + 48 * MB);
  u16* ffh_all = (u16*)(ws + 54 * MB + MB / 2);
  u16* maCat   = (u16*)(ws + 67 * MB + MB / 2);

  // --- prep (converts + adjacency), 1 dispatch ---
  {
    PrepArgs pa = {ope, ma, veh, ope_bf, ma_bf, veh_bf,
                   proc, mask_dyn, A_proc, mv, A_offb,
                   trans, mask_ma, A_on, A_pcing};
    prep_grouped<<<6944, 256, 0, stream>>>(pa);
  }

  // --- weight transposes, 1 dispatch ---
  {
    TrArgs ta = {Wq, Wk, Wv, Wo, ffW1, ffW2, maprojW,
                 WqT, WkT, WvT, WoT, ffW1T, ffW2T, maprojT};
    transpose_all<<<2176, 256, 0, stream>>>(ta);
  }

  const size_t MA_OUT  = (size_t)NBATCH * NOPE * EDIM;
  const size_t VEH_OUT = MA_OUT + (size_t)NBATCH * NMA * EDIM;

  const u16* rowbf[4] = {ope_bf, veh_bf, ma_bf, ma_bf};
  const float* costp[4] = {A_proc, A_offb, A_pcing, A_on};

  // --- grouped GEMM #1: q(x4) + k(x4) + v(x4) ---
  {
    GGArgs ga; ga.n = 12;
    int wg = 0;
    for (int i = 0; i < 4; i++) {
      ga.g[i] = {rowbf[i], WqT + (size_t)i * 65536, nullptr,
                 q_all + (size_t)OFF[i] * 256, MS4[i], 256, 256, 0, wg, 2};
      wg += (MS4[i] / 128) * 2;
    }
    for (int i = 0; i < 4; i++) {
      ga.g[4 + i] = {ma_bf, WkT + (size_t)i * 65536, nullptr,
                     k_all + (size_t)i * 524288, 2048, 256, 256, 0, wg, 2};
      wg += 32;
    }
    for (int i = 0; i < 4; i++) {
      ga.g[8 + i] = {ma_bf, WvT + (size_t)i * 65536, nullptr,
                     v_all + (size_t)i * 524288, 2048, 256, 256, 0, wg, 2};
      wg += 32;
    }
    gemm_grouped<<<wg, 256, 0, stream>>>(ga);
  }

  transpose_v<<<dim3(8, 4, 64), 256, 0, stream>>>(v_all, vT_all);

  // --- grouped attention: 832 blocks (16-row tiles) ---
  {
    AGArgs aa;
    int wg = 0;
    const int R4[4] = {NOPE, NVEH, NMA, NMA};
    for (int i = 0; i < 4; i++) {
      aa.g[i] = {q_all + (size_t)OFF[i] * 256, k_all + (size_t)i * 524288,
                 vT_all + (size_t)i * 524288, costp[i],
                 ctx_all + (size_t)OFF[i] * 256,
                 mixW1 + (size_t)i * 256, mixb1 + (size_t)i * 128,
                 mixW2 + (size_t)i * 128, mixb2 + (size_t)i * 16,
                 R4[i], wg};
      wg += MS4[i] / 16;
    }
    attn_grouped<<<wg, 256, 0, stream>>>(aa);
  }

  // --- Wo ---
  {
    GGArgs ga; ga.n = 4;
    int wg = 0;
    for (int i = 0; i < 4; i++) {
      ga.g[i] = {ctx_all + (size_t)OFF[i] * 256, WoT + (size_t)i * 65536,
                 nullptr, t1_all + (size_t)OFF[i] * 256,
                 MS4[i], 256, 256, 0, wg, 2};
      wg += (MS4[i] / 128) * 2;
    }
    gemm_grouped<<<wg, 256, 0, stream>>>(ga);
  }

  {
    LN1Args la = {ope, veh, ma, ma, 8192, 9216, 11264};
    ln1_grouped<<<TOT, 256, 0, stream>>>(la, t1_all, out1_all);
  }

  // --- FF1 (bias+relu) ---
  {
    GGArgs ga; ga.n = 4;
    int wg = 0;
    for (int i = 0; i < 4; i++) {
      ga.g[i] = {out1_all + (size_t)OFF[i] * 256, ffW1T + (size_t)i * 131072,
                 ffb1 + (size_t)i * 512, ffh_all + (size_t)OFF[i] * 512,
                 MS4[i], 512, 256, 2, wg, 4};
      wg += (MS4[i] / 128) * 4;
    }
    gemm_grouped<<<wg, 256, 0, stream>>>(ga);
  }

  // --- FF2 (bias) ---
  {
    GGArgs ga; ga.n = 4;
    int wg = 0;
    for (int i = 0; i < 4; i++) {
      ga.g[i] = {ffh_all + (size_t)OFF[i] * 512, ffW2T + (size_t)i * 131072,
                 ffb2 + (size_t)i * 256, t1_all + (size_t)OFF[i] * 256,
                 MS4[i], 256, 512, 1, wg, 2};
      wg += (MS4[i] / 128) * 2;
    }
    gemm_grouped<<<wg, 256, 0, stream>>>(ga);
  }

  {
    LN2Args la = {out, out + VEH_OUT, maCat, maCat, 8192, 9216, 11264};
    ln2_grouped<<<TOT, 256, 0, stream>>>(la, out1_all, t1_all);
  }

  gemm_mfma_f32<<<dim3(2, 16), 256, 0, stream>>>(maCat, maprojT, maprojb,
      out + MA_OUT, 2048, 256, 512);
}